// Round 4
// baseline (705.179 us; speedup 1.0000x reference)
//
#include <hip/hip_runtime.h>

typedef __attribute__((ext_vector_type(8))) _Float16 f16x8;
typedef __attribute__((ext_vector_type(4))) _Float16 f16x4;
typedef __attribute__((ext_vector_type(8))) short bf16x8;
typedef __attribute__((ext_vector_type(4))) float f32x4;
typedef __attribute__((ext_vector_type(4))) unsigned short u16x4;
typedef __attribute__((ext_vector_type(4))) float fx4;

#define D_MODEL 1024
#define N_HEADS 16
#define SEQ 2048
#define TOKENS 4096
#define N_EXP 8
#define EHID 512
#define LO_S 2048.0f
#define INV_LO (1.0f / 2048.0f)
#define QSCALE 0.18033688011112043f   // 0.125 * log2(e) folded into Q
#define DTHR 11.0f                    // defer-max threshold (log2 domain): P <= 2^11

__device__ inline unsigned short f2bf(float f) {
  union { float f; unsigned u; } v; v.f = f;
  unsigned u = v.u;
  return (unsigned short)((u + 0x7FFFu + ((u >> 16) & 1u)) >> 16);
}

__device__ inline void split16(float v, _Float16& h, _Float16& l) {
  h = (_Float16)v;
  l = (_Float16)((v - (float)h) * LO_S);
}

__device__ inline void gload_lds16(const void* g, void* lds) {
  __builtin_amdgcn_global_load_lds((const __attribute__((address_space(1))) void*)g,
                                   (__attribute__((address_space(3))) void*)lds, 16, 0, 0);
}

// ---------------- LayerNorm -> split fp16 planes ----------------
__global__ __launch_bounds__(256) void ln_f16s_kernel(const float* __restrict__ x, const float* __restrict__ g,
                                                      const float* __restrict__ b,
                                                      _Float16* __restrict__ xh, _Float16* __restrict__ xl) {
  int t = blockIdx.x, tid = threadIdx.x;
  const float* row = x + (size_t)t * D_MODEL;
  fx4 v = *(const fx4*)(row + tid * 4);
  float s = v[0] + v[1] + v[2] + v[3];
  float s2 = v[0]*v[0] + v[1]*v[1] + v[2]*v[2] + v[3]*v[3];
  #pragma unroll
  for (int off = 1; off < 64; off <<= 1) { s += __shfl_xor(s, off); s2 += __shfl_xor(s2, off); }
  __shared__ float red[8];
  int wv = tid >> 6, wl = tid & 63;
  if (wl == 0) { red[wv] = s; red[4 + wv] = s2; }
  __syncthreads();
  s = red[0] + red[1] + red[2] + red[3];
  s2 = red[4] + red[5] + red[6] + red[7];
  float mu = s * (1.f / 1024.f);
  float var = s2 * (1.f / 1024.f) - mu * mu;
  float rstd = rsqrtf(var + 1e-5f);
  int kk = tid * 4;
  f16x4 oh, ol;
  #pragma unroll
  for (int c = 0; c < 4; c++) {
    float y = (v[c] - mu) * rstd * g[kk + c] + b[kk + c];
    _Float16 h, lo; split16(y, h, lo);
    oh[c] = h; ol[c] = lo;
  }
  *(f16x4*)(xh + (size_t)t * D_MODEL + kk) = oh;
  *(f16x4*)(xl + (size_t)t * D_MODEL + kk) = ol;
}

// ---------------- transpose + split-fp16 cast: dst[C][R] = src[R][C] ----------------
__global__ __launch_bounds__(256) void tcast_f16s_kernel(const float* __restrict__ src,
                                                         _Float16* __restrict__ dh, _Float16* __restrict__ dl,
                                                         int R, int C) {
  __shared__ float tile[32][33];
  size_t mo = (size_t)blockIdx.z * R * C;
  src += mo; dh += mo; dl += mo;
  int c0 = blockIdx.x * 32, r0 = blockIdx.y * 32;
  int tx = threadIdx.x & 31, ty = threadIdx.x >> 5;
  #pragma unroll
  for (int i = 0; i < 4; i++) tile[ty + 8*i][tx] = src[(size_t)(r0 + ty + 8*i) * C + c0 + tx];
  __syncthreads();
  #pragma unroll
  for (int i = 0; i < 4; i++) {
    float v = tile[tx][ty + 8*i];
    _Float16 h, lo; split16(v, h, lo);
    size_t idx = (size_t)(c0 + ty + 8*i) * R + r0 + tx;
    dh[idx] = h; dl[idx] = lo;
  }
}

// ---------------- transpose + bf16 cast (MoE weights) ----------------
__global__ __launch_bounds__(256) void tcast_bf16_kernel(const float* __restrict__ src, unsigned short* __restrict__ dst,
                                                         int R, int C) {
  __shared__ float tile[32][33];
  size_t mo = (size_t)blockIdx.z * R * C;
  src += mo; dst += mo;
  int c0 = blockIdx.x * 32, r0 = blockIdx.y * 32;
  int tx = threadIdx.x & 31, ty = threadIdx.x >> 5;
  #pragma unroll
  for (int i = 0; i < 4; i++) tile[ty + 8*i][tx] = src[(size_t)(r0 + ty + 8*i) * C + c0 + tx];
  __syncthreads();
  #pragma unroll
  for (int i = 0; i < 4; i++) dst[(size_t)(c0 + ty + 8*i) * R + r0 + tx] = f2bf(tile[tx][ty + 8*i]);
}

// ---------------- split-fp16 128x128 GEMM core (swizzled LDS via pre-swizzled source) ----------------
__device__ inline void gemm128s(const _Float16* __restrict__ Ah, const _Float16* __restrict__ Al,
                                const _Float16* __restrict__ Bh, const _Float16* __restrict__ Bl,
                                int lda, int ldb, int K, int bm, int bn,
                                _Float16* ls, f32x4 (&acc)[4][4], f32x4 (&accx)[4][4]) {
  const int tid = threadIdx.x, w = tid >> 6, l = tid & 63, lr = l & 15, lg = l >> 4;
  const int wr = (w >> 1) * 64, wc = (w & 1) * 64;
  // pre-swizzled source column: dest slot s=tid&3 of row tid>>2 receives global slot s^((row>>1)&3)
  int ca = (((tid & 3) ^ ((tid >> 3) & 3)) * 8);
  int ra0 = tid >> 2, ra1 = 64 + (tid >> 2);
  const _Float16* gAh0 = Ah + (size_t)(bm + ra0) * lda + ca;
  const _Float16* gAh1 = Ah + (size_t)(bm + ra1) * lda + ca;
  const _Float16* gAl0 = Al + (size_t)(bm + ra0) * lda + ca;
  const _Float16* gAl1 = Al + (size_t)(bm + ra1) * lda + ca;
  const _Float16* gBh0 = Bh + (size_t)(bn + ra0) * ldb + ca;
  const _Float16* gBh1 = Bh + (size_t)(bn + ra1) * ldb + ca;
  const _Float16* gBl0 = Bl + (size_t)(bn + ra0) * ldb + ca;
  const _Float16* gBl1 = Bl + (size_t)(bn + ra1) * ldb + ca;
  char* base = (char*)ls;
  char* dAh0 = base + w * 1024;          char* dAh1 = base + 4096 + w * 1024;
  char* dAl0 = base + 8192 + w * 1024;   char* dAl1 = base + 12288 + w * 1024;
  char* dBh0 = base + 16384 + w * 1024;  char* dBh1 = base + 20480 + w * 1024;
  char* dBl0 = base + 24576 + w * 1024;  char* dBl1 = base + 28672 + w * 1024;
  const int swz = ((lg ^ ((lr >> 1) & 3)) << 3);   // swizzled element col for frag reads
  for (int ko = 0; ko < K; ko += 32) {
    gload_lds16(gAh0 + ko, dAh0); gload_lds16(gAh1 + ko, dAh1);
    gload_lds16(gAl0 + ko, dAl0); gload_lds16(gAl1 + ko, dAl1);
    gload_lds16(gBh0 + ko, dBh0); gload_lds16(gBh1 + ko, dBh1);
    gload_lds16(gBl0 + ko, dBl0); gload_lds16(gBl1 + ko, dBl1);
    __syncthreads();
    f16x8 ah[4], al4[4], bh4[4], bl4[4];
    #pragma unroll
    for (int m = 0; m < 4; m++) {
      ah[m]  = *(const f16x8*)(ls + (wr + m*16 + lr) * 32 + swz);
      al4[m] = *(const f16x8*)(ls + 4096 + (wr + m*16 + lr) * 32 + swz);
    }
    #pragma unroll
    for (int n = 0; n < 4; n++) {
      bh4[n] = *(const f16x8*)(ls + 8192 + (wc + n*16 + lr) * 32 + swz);
      bl4[n] = *(const f16x8*)(ls + 12288 + (wc + n*16 + lr) * 32 + swz);
    }
    #pragma unroll
    for (int m = 0; m < 4; m++)
      #pragma unroll
      for (int n = 0; n < 4; n++) {
        acc[m][n]  = __builtin_amdgcn_mfma_f32_16x16x32_f16(ah[m], bh4[n], acc[m][n], 0, 0, 0);
        accx[m][n] = __builtin_amdgcn_mfma_f32_16x16x32_f16(ah[m], bl4[n], accx[m][n], 0, 0, 0);
        accx[m][n] = __builtin_amdgcn_mfma_f32_16x16x32_f16(al4[m], bh4[n], accx[m][n], 0, 0, 0);
      }
    __syncthreads();
  }
}

// ---------------- QKV GEMM -> q (pre-scaled),k [BH][S][64] hi/lo, vT [BH][64][S] hi/lo ----------------
__global__ __launch_bounds__(256) void gemm_qkv_kernel(const _Float16* __restrict__ xh, const _Float16* __restrict__ xl,
                                                       const _Float16* __restrict__ Wh, const _Float16* __restrict__ Wl,
                                                       _Float16* __restrict__ qh, _Float16* __restrict__ ql,
                                                       _Float16* __restrict__ kh, _Float16* __restrict__ kl,
                                                       _Float16* __restrict__ vh, _Float16* __restrict__ vl) {
  __shared__ _Float16 ls[16384];
  f32x4 acc[4][4] = {}, accx[4][4] = {};
  int bm = blockIdx.x * 128, bn = blockIdx.y * 128;
  gemm128s(xh, xl, Wh, Wl, 1024, 1024, 1024, bm, bn, ls, acc, accx);
  const int tid = threadIdx.x, w = tid >> 6, l = tid & 63, lr = l & 15, lg = l >> 4;
  const int wr = (w >> 1) * 64, wc = (w & 1) * 64;
  #pragma unroll
  for (int m = 0; m < 4; m++) {
    int row0 = bm + wr + m * 16 + lg * 4;
    #pragma unroll
    for (int n = 0; n < 4; n++) {
      int col = bn + wc + n * 16 + lr;
      int mat = col >> 10;
      int c = col & 1023, h = c >> 6, d = c & 63;
      if (mat == 2) {
        int bb = row0 >> 11, ss = row0 & 2047;
        f16x4 ph, pl;
        #pragma unroll
        for (int j = 0; j < 4; j++) {
          float v = acc[m][n][j] + accx[m][n][j] * INV_LO;
          _Float16 hh, ll; split16(v, hh, ll);
          ph[j] = hh; pl[j] = ll;
        }
        size_t idx = ((size_t)(bb * N_HEADS + h) * 64 + d) * SEQ + ss;
        *(f16x4*)(vh + idx) = ph;
        *(f16x4*)(vl + idx) = pl;
      } else {
        _Float16* dsth = (mat == 0) ? qh : kh;
        _Float16* dstl = (mat == 0) ? ql : kl;
        float sc = (mat == 0) ? QSCALE : 1.0f;
        #pragma unroll
        for (int j = 0; j < 4; j++) {
          float v = (acc[m][n][j] + accx[m][n][j] * INV_LO) * sc;
          _Float16 hh, ll; split16(v, hh, ll);
          int t = row0 + j, bb = t >> 11, ss = t & 2047;
          size_t idx = ((size_t)(bb * N_HEADS + h) * SEQ + ss) * 64 + d;
          dsth[idx] = hh; dstl[idx] = ll;
        }
      }
    }
  }
}

// ---------------- Flash attention: 128q block, 4 waves x 32q, KVBLK=64, 128B-row swizzled LDS ----------------
__global__ __launch_bounds__(256) void flash_kernel(const _Float16* __restrict__ qhp, const _Float16* __restrict__ qlp,
                                                    const _Float16* __restrict__ khp, const _Float16* __restrict__ klp,
                                                    const _Float16* __restrict__ vhp, const _Float16* __restrict__ vlp,
                                                    _Float16* __restrict__ oh, _Float16* __restrict__ ol) {
  __shared__ _Float16 lsKh[64 * 64], lsKl[64 * 64];
  __shared__ _Float16 lsVh[64 * 64], lsVl[64 * 64];
  __shared__ _Float16 lsP[4][2][32 * 64];
  int bh = blockIdx.y, qt = blockIdx.x;
  int tid = threadIdx.x, w = tid >> 6, l = tid & 63, lr = l & 15, lg = l >> 4;
  const _Float16* qhb = qhp + (size_t)bh * SEQ * 64;
  const _Float16* qlb = qlp + (size_t)bh * SEQ * 64;
  const _Float16* khb = khp + (size_t)bh * SEQ * 64;
  const _Float16* klb = klp + (size_t)bh * SEQ * 64;
  const _Float16* vhb = vhp + (size_t)bh * 64 * SEQ;
  const _Float16* vlb = vlp + (size_t)bh * 64 * SEQ;
  int q0 = qt * 128 + w * 32;
  f16x8 qfh[2][2], qfl[2][2];
  #pragma unroll
  for (int nf = 0; nf < 2; nf++)
    #pragma unroll
    for (int ks = 0; ks < 2; ks++) {
      size_t idx = (size_t)(q0 + nf*16 + lr) * 64 + ks * 32 + lg * 8;
      qfh[nf][ks] = *(const f16x8*)(qhb + idx);
      qfl[nf][ks] = *(const f16x8*)(qlb + idx);
    }

  f32x4 acc[4][2] = {}, accx[4][2] = {};
  float mst[2] = {-1e30f, -1e30f};
  float lst[2] = {0.f, 0.f};

  // staging: row = tid>>2 (64 rows), two 16B slots {2s, 2s+1}, s = tid&3; swizzle slot^(row&7)
  int srow = tid >> 2, sseg = tid & 3;
  const _Float16* gK0 = khb + (size_t)srow * 64 + sseg * 16;
  const _Float16* gK1 = klb + (size_t)srow * 64 + sseg * 16;
  const _Float16* gV0 = vhb + (size_t)srow * SEQ + sseg * 16;
  const _Float16* gV1 = vlb + (size_t)srow * SEQ + sseg * 16;
  int so0 = srow * 128 + ((((2 * sseg) ^ (srow & 7)) << 4));
  int so1 = srow * 128 + ((((2 * sseg + 1) ^ (srow & 7)) << 4));

  fx4 rk0 = *(const fx4*)(gK0);      fx4 rk1 = *(const fx4*)(gK0 + 8);
  fx4 rl0 = *(const fx4*)(gK1);      fx4 rl1 = *(const fx4*)(gK1 + 8);
  fx4 rv0 = *(const fx4*)(gV0);      fx4 rv1 = *(const fx4*)(gV0 + 8);
  fx4 rw0 = *(const fx4*)(gV1);      fx4 rw1 = *(const fx4*)(gV1 + 8);

  for (int kv0 = 0; kv0 < SEQ; kv0 += 64) {
    __syncthreads();
    *(fx4*)((char*)lsKh + so0) = rk0;  *(fx4*)((char*)lsKh + so1) = rk1;
    *(fx4*)((char*)lsKl + so0) = rl0;  *(fx4*)((char*)lsKl + so1) = rl1;
    *(fx4*)((char*)lsVh + so0) = rv0;  *(fx4*)((char*)lsVh + so1) = rv1;
    *(fx4*)((char*)lsVl + so0) = rw0;  *(fx4*)((char*)lsVl + so1) = rw1;
    __syncthreads();

    // ---- QK^T ----
    f32x4 s[4][2] = {}, sx[4][2] = {};
    #pragma unroll
    for (int ks = 0; ks < 2; ks++) {
      f16x8 kfh[4], kfl[4];
      #pragma unroll
      for (int m = 0; m < 4; m++) {
        int row = m * 16 + lr;
        int off = row * 128 + ((((ks * 4 + lg) ^ (row & 7)) << 4));
        kfh[m] = *(const f16x8*)((char*)lsKh + off);
        kfl[m] = *(const f16x8*)((char*)lsKl + off);
      }
      __builtin_amdgcn_s_setprio(1);
      #pragma unroll
      for (int m = 0; m < 4; m++)
        #pragma unroll
        for (int nf = 0; nf < 2; nf++) {
          s[m][nf]  = __builtin_amdgcn_mfma_f32_16x16x32_f16(kfh[m], qfh[nf][ks], s[m][nf], 0, 0, 0);
          sx[m][nf] = __builtin_amdgcn_mfma_f32_16x16x32_f16(kfh[m], qfl[nf][ks], sx[m][nf], 0, 0, 0);
          sx[m][nf] = __builtin_amdgcn_mfma_f32_16x16x32_f16(kfl[m], qfh[nf][ks], sx[m][nf], 0, 0, 0);
        }
      __builtin_amdgcn_s_setprio(0);
    }

    // prefetch next tile into regs (hides under softmax + PV)
    if (kv0 + 64 < SEQ) {
      const _Float16* nK0 = gK0 + (size_t)(kv0 + 64) * 64;
      const _Float16* nK1 = gK1 + (size_t)(kv0 + 64) * 64;
      rk0 = *(const fx4*)(nK0);             rk1 = *(const fx4*)(nK0 + 8);
      rl0 = *(const fx4*)(nK1);             rl1 = *(const fx4*)(nK1 + 8);
      rv0 = *(const fx4*)(gV0 + kv0 + 64);  rv1 = *(const fx4*)(gV0 + kv0 + 72);
      rw0 = *(const fx4*)(gV1 + kv0 + 64);  rw1 = *(const fx4*)(gV1 + kv0 + 72);
    }

    // ---- softmax (per nf) ----
    #pragma unroll
    for (int nf = 0; nf < 2; nf++) {
      float tm = -3e38f;
      #pragma unroll
      for (int m = 0; m < 4; m++)
        #pragma unroll
        for (int j = 0; j < 4; j++) {
          s[m][nf][j] += sx[m][nf][j] * INV_LO;
          tm = fmaxf(tm, s[m][nf][j]);
        }
      tm = fmaxf(tm, __shfl_xor(tm, 16));
      tm = fmaxf(tm, __shfl_xor(tm, 32));
      if (!__all(tm - mst[nf] <= DTHR)) {
        float mnew = fmaxf(mst[nf], tm);
        float corr = exp2f(mst[nf] - mnew);
        #pragma unroll
        for (int m2 = 0; m2 < 4; m2++)
          #pragma unroll
          for (int j = 0; j < 4; j++) { acc[m2][nf][j] *= corr; accx[m2][nf][j] *= corr; }
        lst[nf] *= corr;
        mst[nf] = mnew;
      }
      float psum = 0.f;
      int prow = nf * 16 + lr;
      #pragma unroll
      for (int m = 0; m < 4; m++) {
        f16x4 ph, pl;
        #pragma unroll
        for (int j = 0; j < 4; j++) {
          float p = exp2f(s[m][nf][j] - mst[nf]);
          psum += p;
          _Float16 hh, ll; split16(p, hh, ll);
          ph[j] = hh; pl[j] = ll;
        }
        int boff = prow * 128 + ((((2 * m + (lg >> 1)) ^ (lr & 7)) << 4) | ((lg & 1) * 8));
        *(f16x4*)((char*)lsP[w][0] + boff) = ph;
        *(f16x4*)((char*)lsP[w][1] + boff) = pl;
      }
      psum += __shfl_xor(psum, 16);
      psum += __shfl_xor(psum, 32);
      lst[nf] += psum;
    }

    // ---- PV ----
    #pragma unroll
    for (int ks2 = 0; ks2 < 2; ks2++) {
      f16x8 vfh[4], vfl[4], pfh[2], pfl[2];
      #pragma unroll
      for (int m2 = 0; m2 < 4; m2++) {
        int row = m2 * 16 + lr;
        int off = row * 128 + ((((ks2 * 4 + lg) ^ (row & 7)) << 4));
        vfh[m2] = *(const f16x8*)((char*)lsVh + off);
        vfl[m2] = *(const f16x8*)((char*)lsVl + off);
      }
      #pragma unroll
      for (int nf = 0; nf < 2; nf++) {
        int prow = nf * 16 + lr;
        int poff = prow * 128 + ((((ks2 * 4 + lg) ^ (lr & 7)) << 4));
        pfh[nf] = *(const f16x8*)((char*)lsP[w][0] + poff);
        pfl[nf] = *(const f16x8*)((char*)lsP[w][1] + poff);
      }
      __builtin_amdgcn_s_setprio(1);
      #pragma unroll
      for (int m2 = 0; m2 < 4; m2++)
        #pragma unroll
        for (int nf = 0; nf < 2; nf++) {
          acc[m2][nf]  = __builtin_amdgcn_mfma_f32_16x16x32_f16(vfh[m2], pfh[nf], acc[m2][nf], 0, 0, 0);
          accx[m2][nf] = __builtin_amdgcn_mfma_f32_16x16x32_f16(vfh[m2], pfl[nf], accx[m2][nf], 0, 0, 0);
          accx[m2][nf] = __builtin_amdgcn_mfma_f32_16x16x32_f16(vfl[m2], pfh[nf], accx[m2][nf], 0, 0, 0);
        }
      __builtin_amdgcn_s_setprio(0);
    }
  }

  int b = bh >> 4, h = bh & 15;
  #pragma unroll
  for (int nf = 0; nf < 2; nf++) {
    float inv = 1.f / lst[nf];
    int t = b * SEQ + q0 + nf * 16 + lr;
    #pragma unroll
    for (int m2 = 0; m2 < 4; m2++) {
      f16x4 ph, pl;
      #pragma unroll
      for (int j = 0; j < 4; j++) {
        float o = (acc[m2][nf][j] + accx[m2][nf][j] * INV_LO) * inv;
        _Float16 hh, ll; split16(o, hh, ll);
        ph[j] = hh; pl[j] = ll;
      }
      size_t idx = (size_t)t * D_MODEL + h * 64 + m2 * 16 + lg * 4;
      *(f16x4*)(oh + idx) = ph;
      *(f16x4*)(ol + idx) = pl;
    }
  }
}

// ---------------- O-proj GEMM + residual -> d_out (fp32) ----------------
__global__ __launch_bounds__(256) void gemm_oproj_kernel(const _Float16* __restrict__ ah, const _Float16* __restrict__ al,
                                                         const _Float16* __restrict__ Wh, const _Float16* __restrict__ Wl,
                                                         const float* __restrict__ x, float* __restrict__ out) {
  __shared__ _Float16 ls[16384];
  f32x4 acc[4][4] = {}, accx[4][4] = {};
  int bm = blockIdx.x * 128, bn = blockIdx.y * 128;
  gemm128s(ah, al, Wh, Wl, 1024, 1024, 1024, bm, bn, ls, acc, accx);
  const int tid = threadIdx.x, w = tid >> 6, l = tid & 63, lr = l & 15, lg = l >> 4;
  const int wr = (w >> 1) * 64, wc = (w & 1) * 64;
  #pragma unroll
  for (int m = 0; m < 4; m++) {
    int row0 = bm + wr + m * 16 + lg * 4;
    #pragma unroll
    for (int n = 0; n < 4; n++) {
      int col = bn + wc + n * 16 + lr;
      #pragma unroll
      for (int j = 0; j < 4; j++) {
        size_t idx = (size_t)(row0 + j) * D_MODEL + col;
        out[idx] = (acc[m][n][j] + accx[m][n][j] * INV_LO) + x[idx];
      }
    }
  }
}

// ---------------- fused LN2 + xn2(bf16) + gate + top2 (fp32) ----------------
__global__ __launch_bounds__(256) void gate_kernel(const float* __restrict__ x1, const float* __restrict__ Wg,
                                                   const float* __restrict__ g2, const float* __restrict__ b2,
                                                   unsigned short* __restrict__ xn2,
                                                   int* __restrict__ cnt, int* __restrict__ topi,
                                                   float* __restrict__ topw) {
  int t = blockIdx.x * 4 + (threadIdx.x >> 6);
  int l = threadIdx.x & 63;
  const float* row = x1 + (size_t)t * D_MODEL;
  fx4 v[4];
  float s = 0.f, s2 = 0.f;
  #pragma unroll
  for (int i = 0; i < 4; i++) {
    v[i] = *(const fx4*)(row + l * 16 + i * 4);
    #pragma unroll
    for (int c = 0; c < 4; c++) { s += v[i][c]; s2 += v[i][c] * v[i][c]; }
  }
  #pragma unroll
  for (int off = 1; off < 64; off <<= 1) { s += __shfl_xor(s, off); s2 += __shfl_xor(s2, off); }
  float mu = s * (1.f / 1024.f);
  float var = s2 * (1.f / 1024.f) - mu * mu;
  float rstd = rsqrtf(var + 1e-5f);
  float a8[8] = {0,0,0,0,0,0,0,0};
  #pragma unroll
  for (int i = 0; i < 4; i++) {
    u16x4 ox;
    #pragma unroll
    for (int c = 0; c < 4; c++) {
      int kk = l * 16 + i * 4 + c;
      float xv = (v[i][c] - mu) * rstd * g2[kk] + b2[kk];
      ox[c] = f2bf(xv);
      const float* wr_ = Wg + (size_t)kk * 8;
      fx4 wa = *(const fx4*)wr_;
      fx4 wb = *(const fx4*)(wr_ + 4);
      a8[0] += xv * wa[0]; a8[1] += xv * wa[1]; a8[2] += xv * wa[2]; a8[3] += xv * wa[3];
      a8[4] += xv * wb[0]; a8[5] += xv * wb[1]; a8[6] += xv * wb[2]; a8[7] += xv * wb[3];
    }
    *(u16x4*)(xn2 + (size_t)t * D_MODEL + l * 16 + i * 4) = ox;
  }
  #pragma unroll
  for (int e = 0; e < 8; e++)
    #pragma unroll
    for (int off = 1; off < 64; off <<= 1) a8[e] += __shfl_xor(a8[e], off);
  if (l == 0) {
    int i0 = 0; float v0 = a8[0];
    #pragma unroll
    for (int e = 1; e < 8; e++) if (a8[e] > v0) { v0 = a8[e]; i0 = e; }
    int i1 = -1; float v1 = -3.4e38f;
    #pragma unroll
    for (int e = 0; e < 8; e++) if (e != i0 && a8[e] > v1) { v1 = a8[e]; i1 = e; }
    float p0 = 1.f / (1.f + __expf(v1 - v0));
    topi[t * 2] = i0; topi[t * 2 + 1] = i1;
    topw[t * 2] = p0; topw[t * 2 + 1] = 1.f - p0;
    atomicAdd(&cnt[i0], 1); atomicAdd(&cnt[i1], 1);
  }
}

__global__ void init_kernel(int* cnt, int* perm) {
  int i = blockIdx.x * 256 + threadIdx.x;
  if (i < 8) cnt[i] = 0;
  if (i < 8448) perm[i] = 0;
}

__global__ void offsets_kernel(const int* __restrict__ cnt, int* __restrict__ poff) {
  if (threadIdx.x == 0) {
    int a = 0;
    for (int e = 0; e < 8; e++) { poff[e] = a; a += ((cnt[e] + 31) >> 5) << 5; }
  }
}

// stable partition of the 8192 (token,k) assignments by expert -> deterministic
__global__ __launch_bounds__(256) void scatter_kernel(const int* __restrict__ topi,
                                                      const int* __restrict__ poff, int* __restrict__ perm,
                                                      int* __restrict__ slot_of) {
  int e = blockIdx.x, tid = threadIdx.x;
  __shared__ int basesh;
  __shared__ int wsum[4];
  if (tid == 0) basesh = poff[e];
  __syncthreads();
  for (int seg = 0; seg < 8192; seg += 256) {
    int a = seg + tid;
    int match = (topi[a] == e) ? 1 : 0;
    unsigned long long bal = __ballot(match);
    int wl = tid & 63, wv = tid >> 6;
    int lanepre = __popcll(bal & ((1ULL << wl) - 1ULL));
    if (wl == 0) wsum[wv] = __popcll(bal);
    __syncthreads();
    int wpre = 0;
    for (int i = 0; i < wv; i++) wpre += wsum[i];
    int total = wsum[0] + wsum[1] + wsum[2] + wsum[3];
    if (match) {
      int pos = basesh + wpre + lanepre;
      perm[pos] = a >> 1;
      slot_of[a] = pos;
    }
    __syncthreads();
    if (tid == 0) basesh += total;
    __syncthreads();
  }
}

// ---------------- MoE FFN: 32-token tile, fused W1->relu->W2, writes y[slot][1024] ----------------
__global__ __launch_bounds__(256) void moe_ffn_kernel(const unsigned short* __restrict__ xn2,
                                                      const unsigned short* __restrict__ W1T,
                                                      const unsigned short* __restrict__ W2T,
                                                      const int* __restrict__ cnt, const int* __restrict__ poff,
                                                      const int* __restrict__ perm,
                                                      float* __restrict__ y) {
  int bid = blockIdx.x;
  int e = -1, lt = bid;
  for (int i = 0; i < 8; i++) {
    int nt = (cnt[i] + 31) >> 5;
    if (lt < nt) { e = i; break; }
    lt -= nt;
  }
  if (e < 0) return;
  int slot0 = poff[e] + lt * 32;

  __shared__ int t_sh[32];
  __shared__ unsigned short lsX[32 * 32];
  __shared__ unsigned short hsh[32 * 520];
  int tid = threadIdx.x, w = tid >> 6, l = tid & 63, lr = l & 15, lg = l >> 4;
  if (tid < 32) t_sh[tid] = perm[slot0 + tid];
  __syncthreads();

  int Xr = tid >> 2;
  int Xc = (((tid & 3) ^ ((tid >> 3) & 3)) * 8);
  const unsigned short* gX = xn2 + (size_t)(tid < 128 ? t_sh[Xr & 31] : 0) * D_MODEL + Xc;
  const unsigned short* W1e = W1T + (size_t)e * EHID * D_MODEL;
  const unsigned short* W2e = W2T + (size_t)e * D_MODEL * EHID;
  const int swz = ((lg ^ ((lr >> 1) & 3)) << 3);

  f32x4 acc[2][8] = {};
  for (int ko = 0; ko < D_MODEL; ko += 32) {
    if (tid < 128) gload_lds16(gX + ko, (char*)lsX + w * 1024);
    __syncthreads();
    bf16x8 a[2];
    #pragma unroll
    for (int m = 0; m < 2; m++) a[m] = *(const bf16x8*)(lsX + (m*16 + lr) * 32 + swz);
    #pragma unroll
    for (int n = 0; n < 8; n++) {
      bf16x8 bb = *(const bf16x8*)(W1e + (size_t)(w * 128 + n * 16 + lr) * D_MODEL + ko + lg * 8);
      #pragma unroll
      for (int m = 0; m < 2; m++)
        acc[m][n] = __builtin_amdgcn_mfma_f32_16x16x32_bf16(a[m], bb, acc[m][n], 0, 0, 0);
    }
    __syncthreads();
  }
  #pragma unroll
  for (int m = 0; m < 2; m++)
    #pragma unroll
    for (int n = 0; n < 8; n++)
      #pragma unroll
      for (int j = 0; j < 4; j++)
        hsh[(m*16 + lg*4 + j) * 520 + w * 128 + n * 16 + lr] = f2bf(fmaxf(acc[m][n][j], 0.f));
  __syncthreads();

  for (int p = 0; p < 2; p++) {
    f32x4 acc2[2][8] = {};
    for (int k2 = 0; k2 < EHID; k2 += 32) {
      bf16x8 a2[2];
      #pragma unroll
      for (int m = 0; m < 2; m++) a2[m] = *(const bf16x8*)(hsh + (m*16 + lr) * 520 + k2 + lg * 8);
      #pragma unroll
      for (int n = 0; n < 8; n++) {
        int ycol = w * 256 + p * 128 + n * 16 + lr;
        bf16x8 bb = *(const bf16x8*)(W2e + (size_t)ycol * EHID + k2 + lg * 8);
        #pragma unroll
        for (int m = 0; m < 2; m++)
          acc2[m][n] = __builtin_amdgcn_mfma_f32_16x16x32_bf16(a2[m], bb, acc2[m][n], 0, 0, 0);
      }
    }
    #pragma unroll
    for (int m = 0; m < 2; m++)
      #pragma unroll
      for (int j = 0; j < 4; j++) {
        int r = m * 16 + lg * 4 + j;
        #pragma unroll
        for (int n = 0; n < 8; n++)
          y[(size_t)(slot0 + r) * D_MODEL + w * 256 + p * 128 + n * 16 + lr] = acc2[m][n][j];
      }
  }
}

// ---------------- combine: out[t] += w0*y[s0] + w1*y[s1] ----------------
__global__ __launch_bounds__(256) void combine_kernel(const float* __restrict__ y, const int* __restrict__ slot_of,
                                                      const float* __restrict__ topw, float* __restrict__ out) {
  int t = blockIdx.x * 4 + (threadIdx.x >> 6);
  int l = threadIdx.x & 63;
  int s0 = slot_of[t * 2], s1 = slot_of[t * 2 + 1];
  float w0 = topw[t * 2], w1 = topw[t * 2 + 1];
  const float* y0 = y + (size_t)s0 * D_MODEL + l * 16;
  const float* y1 = y + (size_t)s1 * D_MODEL + l * 16;
  float* o = out + (size_t)t * D_MODEL + l * 16;
  #pragma unroll
  for (int i = 0; i < 4; i++) {
    fx4 av = *(const fx4*)(y0 + i * 4);
    fx4 bv = *(const fx4*)(y1 + i * 4);
    fx4 d = *(const fx4*)(o + i * 4);
    #pragma unroll
    for (int j = 0; j < 4; j++) d[j] += w0 * av[j] + w1 * bv[j];
    *(fx4*)(o + i * 4) = d;
  }
}

// ---------------- launcher ----------------
#define MB (1u << 20)
extern "C" void kernel_launch(void* const* d_in, const int* in_sizes, int n_in,
                              void* d_out, int out_size, void* d_ws, size_t ws_size,
                              hipStream_t stream) {
  const float* x  = (const float*)d_in[0];
  const float* Wq = (const float*)d_in[1];
  const float* Wk = (const float*)d_in[2];
  const float* Wv = (const float*)d_in[3];
  const float* Wo = (const float*)d_in[4];
  const float* g1 = (const float*)d_in[5];
  const float* b1 = (const float*)d_in[6];
  const float* g2 = (const float*)d_in[7];
  const float* b2 = (const float*)d_in[8];
  const float* Wg = (const float*)d_in[9];
  const float* W1 = (const float*)d_in[10];
  const float* W2 = (const float*)d_in[11];
  float* out = (float*)d_out;

  char* ws = (char*)d_ws;
  _Float16* xn1h = (_Float16*)(ws + 0*MB);     // later aliased as attn hi plane
  _Float16* xn1l = (_Float16*)(ws + 8*MB);     // later aliased as attn lo plane
  _Float16* Wqkh = (_Float16*)(ws + 16*MB);
  _Float16* Wqkl = (_Float16*)(ws + 22*MB);
  _Float16* Woh  = (_Float16*)(ws + 28*MB);
  _Float16* Wol  = (_Float16*)(ws + 30*MB);
  _Float16* qhb  = (_Float16*)(ws + 32*MB);
  _Float16* qlb  = (_Float16*)(ws + 40*MB);
  _Float16* khb  = (_Float16*)(ws + 48*MB);
  _Float16* klb  = (_Float16*)(ws + 56*MB);
  _Float16* vhb  = (_Float16*)(ws + 64*MB);
  _Float16* vlb  = (_Float16*)(ws + 72*MB);
  unsigned short* xn2 = (unsigned short*)(ws + 80*MB);
  unsigned short* W1T = (unsigned short*)(ws + 88*MB);
  unsigned short* W2T = (unsigned short*)(ws + 96*MB);
  char* misc = ws + 104*MB;
  int*   topi    = (int*)(misc);
  float* topw    = (float*)(misc + 32768);
  int*   slot_of = (int*)(misc + 65536);
  int*   cnt     = (int*)(misc + 98304);
  int*   poff    = (int*)(misc + 98336);
  int*   perm    = (int*)(misc + 98368);
  float* ybuf    = (float*)(ws + 32*MB);       // aliases q/k/v buffers (dead after flash)
  _Float16* attnh = xn1h;
  _Float16* attnl = xn1l;

  // weight prep + routing init
  tcast_f16s_kernel<<<dim3(32, 32, 1), 256, 0, stream>>>(Wq, Wqkh, Wqkl, 1024, 1024);
  tcast_f16s_kernel<<<dim3(32, 32, 1), 256, 0, stream>>>(Wk, Wqkh + 1048576, Wqkl + 1048576, 1024, 1024);
  tcast_f16s_kernel<<<dim3(32, 32, 1), 256, 0, stream>>>(Wv, Wqkh + 2097152, Wqkl + 2097152, 1024, 1024);
  tcast_f16s_kernel<<<dim3(32, 32, 1), 256, 0, stream>>>(Wo, Woh, Wol, 1024, 1024);
  tcast_bf16_kernel<<<dim3(16, 32, 8), 256, 0, stream>>>(W1, W1T, 1024, 512);
  tcast_bf16_kernel<<<dim3(32, 16, 8), 256, 0, stream>>>(W2, W2T, 512, 1024);
  init_kernel<<<33, 256, 0, stream>>>(cnt, perm);

  // attention path (split fp16, ~fp32 accuracy)
  ln_f16s_kernel<<<TOKENS, 256, 0, stream>>>(x, g1, b1, xn1h, xn1l);
  gemm_qkv_kernel<<<dim3(32, 24), 256, 0, stream>>>(xn1h, xn1l, Wqkh, Wqkl, qhb, qlb, khb, klb, vhb, vlb);
  flash_kernel<<<dim3(16, 32), 256, 0, stream>>>(qhb, qlb, khb, klb, vhb, vlb, attnh, attnl);
  gemm_oproj_kernel<<<dim3(32, 8), 256, 0, stream>>>(attnh, attnl, Woh, Wol, x, out);

  // MoE path
  gate_kernel<<<1024, 256, 0, stream>>>(out, Wg, g2, b2, xn2, cnt, topi, topw);
  offsets_kernel<<<1, 64, 0, stream>>>(cnt, poff);
  scatter_kernel<<<8, 256, 0, stream>>>(topi, poff, perm, slot_of);
  moe_ffn_kernel<<<264, 256, 0, stream>>>(xn2, W1T, W2T, cnt, poff, perm, ybuf);
  combine_kernel<<<1024, 256, 0, stream>>>(ybuf, slot_of, topw, out);

  (void)in_sizes; (void)n_in; (void)out_size; (void)ws_size;
}

// Round 5
// 646.630 us; speedup vs baseline: 1.0905x; 1.0905x over previous
//
#include <hip/hip_runtime.h>

typedef __attribute__((ext_vector_type(8))) _Float16 f16x8;
typedef __attribute__((ext_vector_type(4))) _Float16 f16x4;
typedef __attribute__((ext_vector_type(8))) short bf16x8;
typedef __attribute__((ext_vector_type(4))) float f32x4;
typedef __attribute__((ext_vector_type(4))) unsigned short u16x4;
typedef __attribute__((ext_vector_type(4))) float fx4;

#define D_MODEL 1024
#define N_HEADS 16
#define SEQ 2048
#define TOKENS 4096
#define N_EXP 8
#define EHID 512
#define LO_S 2048.0f
#define INV_LO (1.0f / 2048.0f)
#define QSCALE 0.18033688011112043f   // 0.125 * log2(e) folded into Q
#define DTHR 11.0f                    // defer-max threshold (log2 domain): P <= 2^11

__device__ inline unsigned short f2bf(float f) {
  union { float f; unsigned u; } v; v.f = f;
  unsigned u = v.u;
  return (unsigned short)((u + 0x7FFFu + ((u >> 16) & 1u)) >> 16);
}

__device__ inline void split16(float v, _Float16& h, _Float16& l) {
  h = (_Float16)v;
  l = (_Float16)((v - (float)h) * LO_S);
}

__device__ inline void gload_lds16(const void* g, void* lds) {
  __builtin_amdgcn_global_load_lds((const __attribute__((address_space(1))) void*)g,
                                   (__attribute__((address_space(3))) void*)lds, 16, 0, 0);
}

// ---------------- LayerNorm -> split fp16 planes ----------------
__global__ __launch_bounds__(256) void ln_f16s_kernel(const float* __restrict__ x, const float* __restrict__ g,
                                                      const float* __restrict__ b,
                                                      _Float16* __restrict__ xh, _Float16* __restrict__ xl) {
  int t = blockIdx.x, tid = threadIdx.x;
  const float* row = x + (size_t)t * D_MODEL;
  fx4 v = *(const fx4*)(row + tid * 4);
  float s = v[0] + v[1] + v[2] + v[3];
  float s2 = v[0]*v[0] + v[1]*v[1] + v[2]*v[2] + v[3]*v[3];
  #pragma unroll
  for (int off = 1; off < 64; off <<= 1) { s += __shfl_xor(s, off); s2 += __shfl_xor(s2, off); }
  __shared__ float red[8];
  int wv = tid >> 6, wl = tid & 63;
  if (wl == 0) { red[wv] = s; red[4 + wv] = s2; }
  __syncthreads();
  s = red[0] + red[1] + red[2] + red[3];
  s2 = red[4] + red[5] + red[6] + red[7];
  float mu = s * (1.f / 1024.f);
  float var = s2 * (1.f / 1024.f) - mu * mu;
  float rstd = rsqrtf(var + 1e-5f);
  int kk = tid * 4;
  f16x4 oh, ol;
  #pragma unroll
  for (int c = 0; c < 4; c++) {
    float y = (v[c] - mu) * rstd * g[kk + c] + b[kk + c];
    _Float16 h, lo; split16(y, h, lo);
    oh[c] = h; ol[c] = lo;
  }
  *(f16x4*)(xh + (size_t)t * D_MODEL + kk) = oh;
  *(f16x4*)(xl + (size_t)t * D_MODEL + kk) = ol;
}

// ---------------- fused transpose + split-fp16 cast for Wq/Wk/Wv/Wo ----------------
__global__ __launch_bounds__(256) void tcast4_kernel(const float* __restrict__ s0, const float* __restrict__ s1,
                                                     const float* __restrict__ s2, const float* __restrict__ s3,
                                                     _Float16* __restrict__ qkvh, _Float16* __restrict__ qkvl,
                                                     _Float16* __restrict__ woh, _Float16* __restrict__ wol) {
  int z = blockIdx.z;
  const float* src = (z == 0) ? s0 : (z == 1) ? s1 : (z == 2) ? s2 : s3;
  _Float16* dh = (z < 3) ? qkvh + (size_t)z * 1048576 : woh;
  _Float16* dl = (z < 3) ? qkvl + (size_t)z * 1048576 : wol;
  __shared__ float tile[32][33];
  int c0 = blockIdx.x * 32, r0 = blockIdx.y * 32;
  int tx = threadIdx.x & 31, ty = threadIdx.x >> 5;
  #pragma unroll
  for (int i = 0; i < 4; i++) tile[ty + 8*i][tx] = src[(size_t)(r0 + ty + 8*i) * 1024 + c0 + tx];
  __syncthreads();
  #pragma unroll
  for (int i = 0; i < 4; i++) {
    float v = tile[tx][ty + 8*i];
    _Float16 h, lo; split16(v, h, lo);
    size_t idx = (size_t)(c0 + ty + 8*i) * 1024 + r0 + tx;
    dh[idx] = h; dl[idx] = lo;
  }
}

// ---------------- transpose + bf16 cast (MoE weights) ----------------
__global__ __launch_bounds__(256) void tcast_bf16_kernel(const float* __restrict__ src, unsigned short* __restrict__ dst,
                                                         int R, int C) {
  __shared__ float tile[32][33];
  size_t mo = (size_t)blockIdx.z * R * C;
  src += mo; dst += mo;
  int c0 = blockIdx.x * 32, r0 = blockIdx.y * 32;
  int tx = threadIdx.x & 31, ty = threadIdx.x >> 5;
  #pragma unroll
  for (int i = 0; i < 4; i++) tile[ty + 8*i][tx] = src[(size_t)(r0 + ty + 8*i) * C + c0 + tx];
  __syncthreads();
  #pragma unroll
  for (int i = 0; i < 4; i++) dst[(size_t)(c0 + ty + 8*i) * R + r0 + tx] = f2bf(tile[tx][ty + 8*i]);
}

// ---------------- split-fp16 128x128 GEMM core (swizzled LDS via pre-swizzled source) ----------------
__device__ inline void gemm128s(const _Float16* __restrict__ Ah, const _Float16* __restrict__ Al,
                                const _Float16* __restrict__ Bh, const _Float16* __restrict__ Bl,
                                int lda, int ldb, int K, int bm, int bn,
                                _Float16* ls, f32x4 (&acc)[4][4], f32x4 (&accx)[4][4]) {
  const int tid = threadIdx.x, w = tid >> 6, l = tid & 63, lr = l & 15, lg = l >> 4;
  const int wr = (w >> 1) * 64, wc = (w & 1) * 64;
  int ca = (((tid & 3) ^ ((tid >> 3) & 3)) * 8);
  int ra0 = tid >> 2, ra1 = 64 + (tid >> 2);
  const _Float16* gAh0 = Ah + (size_t)(bm + ra0) * lda + ca;
  const _Float16* gAh1 = Ah + (size_t)(bm + ra1) * lda + ca;
  const _Float16* gAl0 = Al + (size_t)(bm + ra0) * lda + ca;
  const _Float16* gAl1 = Al + (size_t)(bm + ra1) * lda + ca;
  const _Float16* gBh0 = Bh + (size_t)(bn + ra0) * ldb + ca;
  const _Float16* gBh1 = Bh + (size_t)(bn + ra1) * ldb + ca;
  const _Float16* gBl0 = Bl + (size_t)(bn + ra0) * ldb + ca;
  const _Float16* gBl1 = Bl + (size_t)(bn + ra1) * ldb + ca;
  char* base = (char*)ls;
  char* dAh0 = base + w * 1024;          char* dAh1 = base + 4096 + w * 1024;
  char* dAl0 = base + 8192 + w * 1024;   char* dAl1 = base + 12288 + w * 1024;
  char* dBh0 = base + 16384 + w * 1024;  char* dBh1 = base + 20480 + w * 1024;
  char* dBl0 = base + 24576 + w * 1024;  char* dBl1 = base + 28672 + w * 1024;
  const int swz = ((lg ^ ((lr >> 1) & 3)) << 3);
  for (int ko = 0; ko < K; ko += 32) {
    gload_lds16(gAh0 + ko, dAh0); gload_lds16(gAh1 + ko, dAh1);
    gload_lds16(gAl0 + ko, dAl0); gload_lds16(gAl1 + ko, dAl1);
    gload_lds16(gBh0 + ko, dBh0); gload_lds16(gBh1 + ko, dBh1);
    gload_lds16(gBl0 + ko, dBl0); gload_lds16(gBl1 + ko, dBl1);
    __syncthreads();
    f16x8 ah[4], al4[4], bh4[4], bl4[4];
    #pragma unroll
    for (int m = 0; m < 4; m++) {
      ah[m]  = *(const f16x8*)(ls + (wr + m*16 + lr) * 32 + swz);
      al4[m] = *(const f16x8*)(ls + 4096 + (wr + m*16 + lr) * 32 + swz);
    }
    #pragma unroll
    for (int n = 0; n < 4; n++) {
      bh4[n] = *(const f16x8*)(ls + 8192 + (wc + n*16 + lr) * 32 + swz);
      bl4[n] = *(const f16x8*)(ls + 12288 + (wc + n*16 + lr) * 32 + swz);
    }
    __builtin_amdgcn_s_setprio(1);
    #pragma unroll
    for (int m = 0; m < 4; m++)
      #pragma unroll
      for (int n = 0; n < 4; n++) {
        acc[m][n]  = __builtin_amdgcn_mfma_f32_16x16x32_f16(ah[m], bh4[n], acc[m][n], 0, 0, 0);
        accx[m][n] = __builtin_amdgcn_mfma_f32_16x16x32_f16(ah[m], bl4[n], accx[m][n], 0, 0, 0);
        accx[m][n] = __builtin_amdgcn_mfma_f32_16x16x32_f16(al4[m], bh4[n], accx[m][n], 0, 0, 0);
      }
    __builtin_amdgcn_s_setprio(0);
    __syncthreads();
  }
}

// ---------------- QKV GEMM -> q linear (pre-scaled), K/V^T in swizzled 2048-elem tiles ----------------
// K tile t: rows r=kv&31 (128B rows), elem (r,d) at r*64 + (((d>>3)^(r&7))<<3 | (d&7))
// V tile t: rows d (64B rows),        elem (d,kvs) at d*32 + (((kvs>>3)^(d&3))<<3 | (kvs&7))
__global__ __launch_bounds__(256) void gemm_qkv_kernel(const _Float16* __restrict__ xh, const _Float16* __restrict__ xl,
                                                       const _Float16* __restrict__ Wh, const _Float16* __restrict__ Wl,
                                                       _Float16* __restrict__ qh, _Float16* __restrict__ ql,
                                                       _Float16* __restrict__ kh, _Float16* __restrict__ kl,
                                                       _Float16* __restrict__ vh, _Float16* __restrict__ vl) {
  __shared__ _Float16 ls[16384];
  f32x4 acc[4][4] = {}, accx[4][4] = {};
  int bm = blockIdx.x * 128, bn = blockIdx.y * 128;
  gemm128s(xh, xl, Wh, Wl, 1024, 1024, 1024, bm, bn, ls, acc, accx);
  const int tid = threadIdx.x, w = tid >> 6, l = tid & 63, lr = l & 15, lg = l >> 4;
  const int wr = (w >> 1) * 64, wc = (w & 1) * 64;
  #pragma unroll
  for (int m = 0; m < 4; m++) {
    int row0 = bm + wr + m * 16 + lg * 4;
    #pragma unroll
    for (int n = 0; n < 4; n++) {
      int col = bn + wc + n * 16 + lr;
      int mat = col >> 10;
      int c = col & 1023, h = c >> 6, d = c & 63;
      if (mat == 2) {
        int bb = row0 >> 11, ss = row0 & 2047;
        int tile = ss >> 5, kvs = ss & 31;
        f16x4 ph, pl;
        #pragma unroll
        for (int j = 0; j < 4; j++) {
          float v = acc[m][n][j] + accx[m][n][j] * INV_LO;
          _Float16 hh, ll; split16(v, hh, ll);
          ph[j] = hh; pl[j] = ll;
        }
        size_t base = ((size_t)(bb * N_HEADS + h) * 64 + tile) * 2048;
        int off = d * 32 + ((((kvs >> 3) ^ (d & 3)) << 3) | (kvs & 7));
        *(f16x4*)(vh + base + off) = ph;
        *(f16x4*)(vl + base + off) = pl;
      } else if (mat == 1) {
        #pragma unroll
        for (int j = 0; j < 4; j++) {
          float v = acc[m][n][j] + accx[m][n][j] * INV_LO;
          _Float16 hh, ll; split16(v, hh, ll);
          int t = row0 + j, bb = t >> 11, ss = t & 2047;
          int tile = ss >> 5, r = ss & 31;
          size_t base = ((size_t)(bb * N_HEADS + h) * 64 + tile) * 2048;
          int off = r * 64 + ((((d >> 3) ^ (r & 7)) << 3) | (d & 7));
          kh[base + off] = hh; kl[base + off] = ll;
        }
      } else {
        #pragma unroll
        for (int j = 0; j < 4; j++) {
          float v = (acc[m][n][j] + accx[m][n][j] * INV_LO) * QSCALE;
          _Float16 hh, ll; split16(v, hh, ll);
          int t = row0 + j, bb = t >> 11, ss = t & 2047;
          size_t idx = ((size_t)(bb * N_HEADS + h) * SEQ + ss) * 64 + d;
          qh[idx] = hh; ql[idx] = ll;
        }
      }
    }
  }
}

// ---------------- Flash attention: 64q block (4 waves x 16q), KVBLK=32, dbuf gload_lds staging ----------------
__global__ __launch_bounds__(256, 4) void flash_kernel(const _Float16* __restrict__ qhp, const _Float16* __restrict__ qlp,
                                                       const _Float16* __restrict__ khs, const _Float16* __restrict__ kls,
                                                       const _Float16* __restrict__ vhs, const _Float16* __restrict__ vls,
                                                       _Float16* __restrict__ oh, _Float16* __restrict__ ol) {
  __shared__ _Float16 lsKV[2][8192];      // per buf: Kh@0 Kl@2048 Vh@4096 Vl@6144 (f16 elems)
  __shared__ _Float16 lsP[4][2][512];     // per-wave P hi/lo, 16x32 swizzled (64B rows)
  int wgid = blockIdx.x;
  int xcd = wgid & 7, kk = wgid >> 3;
  int bh = xcd * 4 + (kk >> 5), qt = kk & 31;   // XCD-local heads: 4 heads x 1MB K/V = L2-resident
  int tid = threadIdx.x, w = tid >> 6, l = tid & 63, lr = l & 15, lg = l >> 4;
  int q0 = qt * 64 + w * 16;
  const _Float16* qhb = qhp + (size_t)bh * SEQ * 64;
  const _Float16* qlb = qlp + (size_t)bh * SEQ * 64;
  f16x8 qfh[2], qfl[2];
  #pragma unroll
  for (int ks = 0; ks < 2; ks++) {
    size_t idx = (size_t)(q0 + lr) * 64 + ks * 32 + lg * 8;
    qfh[ks] = *(const f16x8*)(qhb + idx);
    qfl[ks] = *(const f16x8*)(qlb + idx);
  }
  const _Float16* splane = (w == 0) ? khs : (w == 1) ? kls : (w == 2) ? vhs : vls;
  const _Float16* sbase = splane + (size_t)bh * 131072 + l * 8;

  f32x4 acc[4] = {}, accx[4] = {};
  float mst = -1e30f, lst = 0.f;

  {
    const _Float16* sp = sbase;
    _Float16* dd = &lsKV[0][w * 2048];
    gload_lds16(sp, dd); gload_lds16(sp + 512, dd + 512);
    gload_lds16(sp + 1024, dd + 1024); gload_lds16(sp + 1536, dd + 1536);
  }
  __syncthreads();

  for (int t = 0; t < 64; t++) {
    int bR = t & 1;
    if (t < 63) {                               // stage next tile into the other buffer
      const _Float16* sp = sbase + (size_t)(t + 1) * 2048;
      _Float16* dd = &lsKV[bR ^ 1][w * 2048];
      gload_lds16(sp, dd); gload_lds16(sp + 512, dd + 512);
      gload_lds16(sp + 1024, dd + 1024); gload_lds16(sp + 1536, dd + 1536);
    }
    char* bufB = (char*)&lsKV[bR][0];

    // ---- QK^T ----
    f32x4 s[2] = {}, sx[2] = {};
    #pragma unroll
    for (int ks = 0; ks < 2; ks++) {
      f16x8 kfh[2], kfl[2];
      #pragma unroll
      for (int m = 0; m < 2; m++) {
        int off = (m * 16 + lr) * 128 + (((ks * 4 + lg) ^ (lr & 7)) << 4);
        kfh[m] = *(const f16x8*)(bufB + off);
        kfl[m] = *(const f16x8*)(bufB + 4096 + off);
      }
      __builtin_amdgcn_s_setprio(1);
      #pragma unroll
      for (int m = 0; m < 2; m++) {
        s[m]  = __builtin_amdgcn_mfma_f32_16x16x32_f16(kfh[m], qfh[ks], s[m], 0, 0, 0);
        sx[m] = __builtin_amdgcn_mfma_f32_16x16x32_f16(kfh[m], qfl[ks], sx[m], 0, 0, 0);
        sx[m] = __builtin_amdgcn_mfma_f32_16x16x32_f16(kfl[m], qfh[ks], sx[m], 0, 0, 0);
      }
      __builtin_amdgcn_s_setprio(0);
    }

    // ---- softmax ----
    float tm = -3e38f;
    #pragma unroll
    for (int m = 0; m < 2; m++)
      #pragma unroll
      for (int j = 0; j < 4; j++) {
        s[m][j] += sx[m][j] * INV_LO;
        tm = fmaxf(tm, s[m][j]);
      }
    tm = fmaxf(tm, __shfl_xor(tm, 16));
    tm = fmaxf(tm, __shfl_xor(tm, 32));
    if (!__all(tm - mst <= DTHR)) {
      float mnew = fmaxf(mst, tm);
      float corr = exp2f(mst - mnew);
      #pragma unroll
      for (int m2 = 0; m2 < 4; m2++)
        #pragma unroll
        for (int j = 0; j < 4; j++) { acc[m2][j] *= corr; accx[m2][j] *= corr; }
      lst *= corr;
      mst = mnew;
    }
    float psum = 0.f;
    #pragma unroll
    for (int m = 0; m < 2; m++) {
      f16x4 ph, pl;
      #pragma unroll
      for (int j = 0; j < 4; j++) {
        float p = exp2f(s[m][j] - mst);
        psum += p;
        _Float16 hh, ll; split16(p, hh, ll);
        ph[j] = hh; pl[j] = ll;
      }
      int boff = lr * 64 + ((((m * 2 + (lg >> 1)) ^ (lr & 3)) << 4) | ((lg & 1) * 8));
      *(f16x4*)((char*)&lsP[w][0][0] + boff) = ph;
      *(f16x4*)((char*)&lsP[w][1][0] + boff) = pl;
    }
    psum += __shfl_xor(psum, 16);
    psum += __shfl_xor(psum, 32);
    lst += psum;

    // ---- PV ----
    int poff = lr * 64 + ((lg ^ (lr & 3)) << 4);
    f16x8 pfh = *(const f16x8*)((char*)&lsP[w][0][0] + poff);
    f16x8 pfl = *(const f16x8*)((char*)&lsP[w][1][0] + poff);
    __builtin_amdgcn_s_setprio(1);
    #pragma unroll
    for (int m2 = 0; m2 < 4; m2++) {
      int voff = (m2 * 16 + lr) * 64 + ((lg ^ (lr & 3)) << 4);
      f16x8 vfh = *(const f16x8*)(bufB + 8192 + voff);
      f16x8 vfl = *(const f16x8*)(bufB + 12288 + voff);
      acc[m2]  = __builtin_amdgcn_mfma_f32_16x16x32_f16(vfh, pfh, acc[m2], 0, 0, 0);
      accx[m2] = __builtin_amdgcn_mfma_f32_16x16x32_f16(vfh, pfl, accx[m2], 0, 0, 0);
      accx[m2] = __builtin_amdgcn_mfma_f32_16x16x32_f16(vfl, pfh, accx[m2], 0, 0, 0);
    }
    __builtin_amdgcn_s_setprio(0);
    __syncthreads();   // waves done with bufR; bufW loads drained -> ready next iter
  }

  float inv = 1.f / lst;
  int b = bh >> 4, h = bh & 15;
  int tkn = b * SEQ + q0 + lr;
  #pragma unroll
  for (int m2 = 0; m2 < 4; m2++) {
    f16x4 ph, pl;
    #pragma unroll
    for (int j = 0; j < 4; j++) {
      float o = (acc[m2][j] + accx[m2][j] * INV_LO) * inv;
      _Float16 hh, ll; split16(o, hh, ll);
      ph[j] = hh; pl[j] = ll;
    }
    size_t idx = (size_t)tkn * D_MODEL + h * 64 + m2 * 16 + lg * 4;
    *(f16x4*)(oh + idx) = ph;
    *(f16x4*)(ol + idx) = pl;
  }
}

// ---------------- O-proj GEMM + residual -> d_out (fp32) ----------------
__global__ __launch_bounds__(256) void gemm_oproj_kernel(const _Float16* __restrict__ ah, const _Float16* __restrict__ al,
                                                         const _Float16* __restrict__ Wh, const _Float16* __restrict__ Wl,
                                                         const float* __restrict__ x, float* __restrict__ out) {
  __shared__ _Float16 ls[16384];
  f32x4 acc[4][4] = {}, accx[4][4] = {};
  int bm = blockIdx.x * 128, bn = blockIdx.y * 128;
  gemm128s(ah, al, Wh, Wl, 1024, 1024, 1024, bm, bn, ls, acc, accx);
  const int tid = threadIdx.x, w = tid >> 6, l = tid & 63, lr = l & 15, lg = l >> 4;
  const int wr = (w >> 1) * 64, wc = (w & 1) * 64;
  #pragma unroll
  for (int m = 0; m < 4; m++) {
    int row0 = bm + wr + m * 16 + lg * 4;
    #pragma unroll
    for (int n = 0; n < 4; n++) {
      int col = bn + wc + n * 16 + lr;
      #pragma unroll
      for (int j = 0; j < 4; j++) {
        size_t idx = (size_t)(row0 + j) * D_MODEL + col;
        out[idx] = (acc[m][n][j] + accx[m][n][j] * INV_LO) + x[idx];
      }
    }
  }
}

// ---------------- fused LN2 + xn2(bf16) + gate + top2 (fp32) ----------------
__global__ __launch_bounds__(256) void gate_kernel(const float* __restrict__ x1, const float* __restrict__ Wg,
                                                   const float* __restrict__ g2, const float* __restrict__ b2,
                                                   unsigned short* __restrict__ xn2,
                                                   int* __restrict__ cnt, int* __restrict__ topi,
                                                   float* __restrict__ topw) {
  int t = blockIdx.x * 4 + (threadIdx.x >> 6);
  int l = threadIdx.x & 63;
  const float* row = x1 + (size_t)t * D_MODEL;
  fx4 v[4];
  float s = 0.f, s2 = 0.f;
  #pragma unroll
  for (int i = 0; i < 4; i++) {
    v[i] = *(const fx4*)(row + l * 16 + i * 4);
    #pragma unroll
    for (int c = 0; c < 4; c++) { s += v[i][c]; s2 += v[i][c] * v[i][c]; }
  }
  #pragma unroll
  for (int off = 1; off < 64; off <<= 1) { s += __shfl_xor(s, off); s2 += __shfl_xor(s2, off); }
  float mu = s * (1.f / 1024.f);
  float var = s2 * (1.f / 1024.f) - mu * mu;
  float rstd = rsqrtf(var + 1e-5f);
  float a8[8] = {0,0,0,0,0,0,0,0};
  #pragma unroll
  for (int i = 0; i < 4; i++) {
    u16x4 ox;
    #pragma unroll
    for (int c = 0; c < 4; c++) {
      int kk = l * 16 + i * 4 + c;
      float xv = (v[i][c] - mu) * rstd * g2[kk] + b2[kk];
      ox[c] = f2bf(xv);
      const float* wr_ = Wg + (size_t)kk * 8;
      fx4 wa = *(const fx4*)wr_;
      fx4 wb = *(const fx4*)(wr_ + 4);
      a8[0] += xv * wa[0]; a8[1] += xv * wa[1]; a8[2] += xv * wa[2]; a8[3] += xv * wa[3];
      a8[4] += xv * wb[0]; a8[5] += xv * wb[1]; a8[6] += xv * wb[2]; a8[7] += xv * wb[3];
    }
    *(u16x4*)(xn2 + (size_t)t * D_MODEL + l * 16 + i * 4) = ox;
  }
  #pragma unroll
  for (int e = 0; e < 8; e++)
    #pragma unroll
    for (int off = 1; off < 64; off <<= 1) a8[e] += __shfl_xor(a8[e], off);
  if (l == 0) {
    int i0 = 0; float v0 = a8[0];
    #pragma unroll
    for (int e = 1; e < 8; e++) if (a8[e] > v0) { v0 = a8[e]; i0 = e; }
    int i1 = -1; float v1 = -3.4e38f;
    #pragma unroll
    for (int e = 0; e < 8; e++) if (e != i0 && a8[e] > v1) { v1 = a8[e]; i1 = e; }
    float p0 = 1.f / (1.f + __expf(v1 - v0));
    topi[t * 2] = i0; topi[t * 2 + 1] = i1;
    topw[t * 2] = p0; topw[t * 2 + 1] = 1.f - p0;
    atomicAdd(&cnt[i0], 1); atomicAdd(&cnt[i1], 1);
  }
}

__global__ void init_kernel(int* cnt, int* perm) {
  int i = blockIdx.x * 256 + threadIdx.x;
  if (i < 8) cnt[i] = 0;
  if (i < 8448) perm[i] = 0;
}

__global__ void offsets_kernel(const int* __restrict__ cnt, int* __restrict__ poff) {
  if (threadIdx.x == 0) {
    int a = 0;
    for (int e = 0; e < 8; e++) { poff[e] = a; a += ((cnt[e] + 31) >> 5) << 5; }
  }
}

// stable partition of the 8192 (token,k) assignments by expert -> deterministic
__global__ __launch_bounds__(256) void scatter_kernel(const int* __restrict__ topi,
                                                      const int* __restrict__ poff, int* __restrict__ perm,
                                                      int* __restrict__ slot_of) {
  int e = blockIdx.x, tid = threadIdx.x;
  __shared__ int basesh;
  __shared__ int wsum[4];
  if (tid == 0) basesh = poff[e];
  __syncthreads();
  for (int seg = 0; seg < 8192; seg += 256) {
    int a = seg + tid;
    int match = (topi[a] == e) ? 1 : 0;
    unsigned long long bal = __ballot(match);
    int wl = tid & 63, wv = tid >> 6;
    int lanepre = __popcll(bal & ((1ULL << wl) - 1ULL));
    if (wl == 0) wsum[wv] = __popcll(bal);
    __syncthreads();
    int wpre = 0;
    for (int i = 0; i < wv; i++) wpre += wsum[i];
    int total = wsum[0] + wsum[1] + wsum[2] + wsum[3];
    if (match) {
      int pos = basesh + wpre + lanepre;
      perm[pos] = a >> 1;
      slot_of[a] = pos;
    }
    __syncthreads();
    if (tid == 0) basesh += total;
    __syncthreads();
  }
}

// ---------------- MoE FFN: 32-token tile, fused W1->relu->W2, writes y[slot][1024] ----------------
__global__ __launch_bounds__(256) void moe_ffn_kernel(const unsigned short* __restrict__ xn2,
                                                      const unsigned short* __restrict__ W1T,
                                                      const unsigned short* __restrict__ W2T,
                                                      const int* __restrict__ cnt, const int* __restrict__ poff,
                                                      const int* __restrict__ perm,
                                                      float* __restrict__ y) {
  int bid = blockIdx.x;
  int e = -1, lt = bid;
  for (int i = 0; i < 8; i++) {
    int nt = (cnt[i] + 31) >> 5;
    if (lt < nt) { e = i; break; }
    lt -= nt;
  }
  if (e < 0) return;
  int slot0 = poff[e] + lt * 32;

  __shared__ int t_sh[32];
  __shared__ unsigned short lsX[32 * 32];
  __shared__ unsigned short hsh[32 * 520];
  int tid = threadIdx.x, w = tid >> 6, l = tid & 63, lr = l & 15, lg = l >> 4;
  if (tid < 32) t_sh[tid] = perm[slot0 + tid];
  __syncthreads();

  int Xr = tid >> 2;
  int Xc = (((tid & 3) ^ ((tid >> 3) & 3)) * 8);
  const unsigned short* gX = xn2 + (size_t)(tid < 128 ? t_sh[Xr & 31] : 0) * D_MODEL + Xc;
  const unsigned short* W1e = W1T + (size_t)e * EHID * D_MODEL;
  const unsigned short* W2e = W2T + (size_t)e * D_MODEL * EHID;
  const int swz = ((lg ^ ((lr >> 1) & 3)) << 3);

  f32x4 acc[2][8] = {};
  for (int ko = 0; ko < D_MODEL; ko += 32) {
    if (tid < 128) gload_lds16(gX + ko, (char*)lsX + w * 1024);
    __syncthreads();
    bf16x8 a[2];
    #pragma unroll
    for (int m = 0; m < 2; m++) a[m] = *(const bf16x8*)(lsX + (m*16 + lr) * 32 + swz);
    #pragma unroll
    for (int n = 0; n < 8; n++) {
      bf16x8 bb = *(const bf16x8*)(W1e + (size_t)(w * 128 + n * 16 + lr) * D_MODEL + ko + lg * 8);
      #pragma unroll
      for (int m = 0; m < 2; m++)
        acc[m][n] = __builtin_amdgcn_mfma_f32_16x16x32_bf16(a[m], bb, acc[m][n], 0, 0, 0);
    }
    __syncthreads();
  }
  #pragma unroll
  for (int m = 0; m < 2; m++)
    #pragma unroll
    for (int n = 0; n < 8; n++)
      #pragma unroll
      for (int j = 0; j < 4; j++)
        hsh[(m*16 + lg*4 + j) * 520 + w * 128 + n * 16 + lr] = f2bf(fmaxf(acc[m][n][j], 0.f));
  __syncthreads();

  for (int p = 0; p < 2; p++) {
    f32x4 acc2[2][8] = {};
    for (int k2 = 0; k2 < EHID; k2 += 32) {
      bf16x8 a2[2];
      #pragma unroll
      for (int m = 0; m < 2; m++) a2[m] = *(const bf16x8*)(hsh + (m*16 + lr) * 520 + k2 + lg * 8);
      #pragma unroll
      for (int n = 0; n < 8; n++) {
        int ycol = w * 256 + p * 128 + n * 16 + lr;
        bf16x8 bb = *(const bf16x8*)(W2e + (size_t)ycol * EHID + k2 + lg * 8);
        #pragma unroll
        for (int m = 0; m < 2; m++)
          acc2[m][n] = __builtin_amdgcn_mfma_f32_16x16x32_bf16(a2[m], bb, acc2[m][n], 0, 0, 0);
      }
    }
    #pragma unroll
    for (int m = 0; m < 2; m++)
      #pragma unroll
      for (int j = 0; j < 4; j++) {
        int r = m * 16 + lg * 4 + j;
        #pragma unroll
        for (int n = 0; n < 8; n++)
          y[(size_t)(slot0 + r) * D_MODEL + w * 256 + p * 128 + n * 16 + lr] = acc2[m][n][j];
      }
  }
}

// ---------------- combine: out[t] += w0*y[s0] + w1*y[s1] ----------------
__global__ __launch_bounds__(256) void combine_kernel(const float* __restrict__ y, const int* __restrict__ slot_of,
                                                      const float* __restrict__ topw, float* __restrict__ out) {
  int t = blockIdx.x * 4 + (threadIdx.x >> 6);
  int l = threadIdx.x & 63;
  int s0 = slot_of[t * 2], s1 = slot_of[t * 2 + 1];
  float w0 = topw[t * 2], w1 = topw[t * 2 + 1];
  const float* y0 = y + (size_t)s0 * D_MODEL + l * 16;
  const float* y1 = y + (size_t)s1 * D_MODEL + l * 16;
  float* o = out + (size_t)t * D_MODEL + l * 16;
  #pragma unroll
  for (int i = 0; i < 4; i++) {
    fx4 av = *(const fx4*)(y0 + i * 4);
    fx4 bv = *(const fx4*)(y1 + i * 4);
    fx4 d = *(const fx4*)(o + i * 4);
    #pragma unroll
    for (int j = 0; j < 4; j++) d[j] += w0 * av[j] + w1 * bv[j];
    *(fx4*)(o + i * 4) = d;
  }
}

// ---------------- launcher ----------------
#define MB (1u << 20)
extern "C" void kernel_launch(void* const* d_in, const int* in_sizes, int n_in,
                              void* d_out, int out_size, void* d_ws, size_t ws_size,
                              hipStream_t stream) {
  const float* x  = (const float*)d_in[0];
  const float* Wq = (const float*)d_in[1];
  const float* Wk = (const float*)d_in[2];
  const float* Wv = (const float*)d_in[3];
  const float* Wo = (const float*)d_in[4];
  const float* g1 = (const float*)d_in[5];
  const float* b1 = (const float*)d_in[6];
  const float* g2 = (const float*)d_in[7];
  const float* b2 = (const float*)d_in[8];
  const float* Wg = (const float*)d_in[9];
  const float* W1 = (const float*)d_in[10];
  const float* W2 = (const float*)d_in[11];
  float* out = (float*)d_out;

  char* ws = (char*)d_ws;
  _Float16* xn1h = (_Float16*)(ws + 0*MB);     // later aliased as attn hi plane
  _Float16* xn1l = (_Float16*)(ws + 8*MB);     // later aliased as attn lo plane
  _Float16* Wqkh = (_Float16*)(ws + 16*MB);
  _Float16* Wqkl = (_Float16*)(ws + 22*MB);
  _Float16* Woh  = (_Float16*)(ws + 28*MB);
  _Float16* Wol  = (_Float16*)(ws + 30*MB);
  _Float16* qhb  = (_Float16*)(ws + 32*MB);
  _Float16* qlb  = (_Float16*)(ws + 40*MB);
  _Float16* khb  = (_Float16*)(ws + 48*MB);
  _Float16* klb  = (_Float16*)(ws + 56*MB);
  _Float16* vhb  = (_Float16*)(ws + 64*MB);
  _Float16* vlb  = (_Float16*)(ws + 72*MB);
  unsigned short* xn2 = (unsigned short*)(ws + 80*MB);
  unsigned short* W1T = (unsigned short*)(ws + 88*MB);
  unsigned short* W2T = (unsigned short*)(ws + 96*MB);
  char* misc = ws + 104*MB;
  int*   topi    = (int*)(misc);
  float* topw    = (float*)(misc + 32768);
  int*   slot_of = (int*)(misc + 65536);
  int*   cnt     = (int*)(misc + 98304);
  int*   poff    = (int*)(misc + 98336);
  int*   perm    = (int*)(misc + 98368);
  float* ybuf    = (float*)(ws + 32*MB);       // aliases q/k/v buffers (dead after flash)
  _Float16* attnh = xn1h;
  _Float16* attnl = xn1l;

  // weight prep + routing init
  tcast4_kernel<<<dim3(32, 32, 4), 256, 0, stream>>>(Wq, Wk, Wv, Wo, Wqkh, Wqkl, Woh, Wol);
  tcast_bf16_kernel<<<dim3(16, 32, 8), 256, 0, stream>>>(W1, W1T, 1024, 512);
  tcast_bf16_kernel<<<dim3(32, 16, 8), 256, 0, stream>>>(W2, W2T, 512, 1024);
  init_kernel<<<33, 256, 0, stream>>>(cnt, perm);

  // attention path (split fp16, ~fp32 accuracy)
  ln_f16s_kernel<<<TOKENS, 256, 0, stream>>>(x, g1, b1, xn1h, xn1l);
  gemm_qkv_kernel<<<dim3(32, 24), 256, 0, stream>>>(xn1h, xn1l, Wqkh, Wqkl, qhb, qlb, khb, klb, vhb, vlb);
  flash_kernel<<<1024, 256, 0, stream>>>(qhb, qlb, khb, klb, vhb, vlb, attnh, attnl);
  gemm_oproj_kernel<<<dim3(32, 8), 256, 0, stream>>>(attnh, attnl, Woh, Wol, x, out);

  // MoE path
  gate_kernel<<<1024, 256, 0, stream>>>(out, Wg, g2, b2, xn2, cnt, topi, topw);
  offsets_kernel<<<1, 64, 0, stream>>>(cnt, poff);
  scatter_kernel<<<8, 256, 0, stream>>>(topi, poff, perm, slot_of);
  moe_ffn_kernel<<<264, 256, 0, stream>>>(xn2, W1T, W2T, cnt, poff, perm, ybuf);
  combine_kernel<<<1024, 256, 0, stream>>>(ybuf, slot_of, topw, out);

  (void)in_sizes; (void)n_in; (void)out_size; (void)ws_size;
}

// Round 6
// 600.194 us; speedup vs baseline: 1.1749x; 1.0774x over previous
//
#include <hip/hip_runtime.h>

typedef __attribute__((ext_vector_type(8))) _Float16 f16x8;
typedef __attribute__((ext_vector_type(4))) _Float16 f16x4;
typedef __attribute__((ext_vector_type(8))) short bf16x8;
typedef __attribute__((ext_vector_type(4))) float f32x4;
typedef __attribute__((ext_vector_type(4))) unsigned short u16x4;
typedef __attribute__((ext_vector_type(4))) float fx4;

#define D_MODEL 1024
#define N_HEADS 16
#define SEQ 2048
#define TOKENS 4096
#define N_EXP 8
#define EHID 512
#define LO_S 2048.0f
#define INV_LO (1.0f / 2048.0f)
#define QSCALE 0.18033688011112043f   // 0.125 * log2(e) folded into Q
#define DTHR 11.0f                    // defer-max threshold (log2 domain): P <= 2^11

__device__ inline unsigned short f2bf(float f) {
  union { float f; unsigned u; } v; v.f = f;
  unsigned u = v.u;
  return (unsigned short)((u + 0x7FFFu + ((u >> 16) & 1u)) >> 16);
}

__device__ inline void split16(float v, _Float16& h, _Float16& l) {
  h = (_Float16)v;
  l = (_Float16)((v - (float)h) * LO_S);
}

__device__ inline void gload_lds16(const void* g, void* lds) {
  __builtin_amdgcn_global_load_lds((const __attribute__((address_space(1))) void*)g,
                                   (__attribute__((address_space(3))) void*)lds, 16, 0, 0);
}

// ---------------- LayerNorm -> split fp16 planes ----------------
__global__ __launch_bounds__(256) void ln_f16s_kernel(const float* __restrict__ x, const float* __restrict__ g,
                                                      const float* __restrict__ b,
                                                      _Float16* __restrict__ xh, _Float16* __restrict__ xl) {
  int t = blockIdx.x, tid = threadIdx.x;
  const float* row = x + (size_t)t * D_MODEL;
  fx4 v = *(const fx4*)(row + tid * 4);
  float s = v[0] + v[1] + v[2] + v[3];
  float s2 = v[0]*v[0] + v[1]*v[1] + v[2]*v[2] + v[3]*v[3];
  #pragma unroll
  for (int off = 1; off < 64; off <<= 1) { s += __shfl_xor(s, off); s2 += __shfl_xor(s2, off); }
  __shared__ float red[8];
  int wv = tid >> 6, wl = tid & 63;
  if (wl == 0) { red[wv] = s; red[4 + wv] = s2; }
  __syncthreads();
  s = red[0] + red[1] + red[2] + red[3];
  s2 = red[4] + red[5] + red[6] + red[7];
  float mu = s * (1.f / 1024.f);
  float var = s2 * (1.f / 1024.f) - mu * mu;
  float rstd = rsqrtf(var + 1e-5f);
  int kk = tid * 4;
  f16x4 oh, ol;
  #pragma unroll
  for (int c = 0; c < 4; c++) {
    float y = (v[c] - mu) * rstd * g[kk + c] + b[kk + c];
    _Float16 h, lo; split16(y, h, lo);
    oh[c] = h; ol[c] = lo;
  }
  *(f16x4*)(xh + (size_t)t * D_MODEL + kk) = oh;
  *(f16x4*)(xl + (size_t)t * D_MODEL + kk) = ol;
}

// ---------------- fused transpose + split-fp16 cast for Wq/Wk/Wv/Wo ----------------
__global__ __launch_bounds__(256) void tcast4_kernel(const float* __restrict__ s0, const float* __restrict__ s1,
                                                     const float* __restrict__ s2, const float* __restrict__ s3,
                                                     _Float16* __restrict__ qkvh, _Float16* __restrict__ qkvl,
                                                     _Float16* __restrict__ woh, _Float16* __restrict__ wol) {
  int z = blockIdx.z;
  const float* src = (z == 0) ? s0 : (z == 1) ? s1 : (z == 2) ? s2 : s3;
  _Float16* dh = (z < 3) ? qkvh + (size_t)z * 1048576 : woh;
  _Float16* dl = (z < 3) ? qkvl + (size_t)z * 1048576 : wol;
  __shared__ float tile[32][33];
  int c0 = blockIdx.x * 32, r0 = blockIdx.y * 32;
  int tx = threadIdx.x & 31, ty = threadIdx.x >> 5;
  #pragma unroll
  for (int i = 0; i < 4; i++) tile[ty + 8*i][tx] = src[(size_t)(r0 + ty + 8*i) * 1024 + c0 + tx];
  __syncthreads();
  #pragma unroll
  for (int i = 0; i < 4; i++) {
    float v = tile[tx][ty + 8*i];
    _Float16 h, lo; split16(v, h, lo);
    size_t idx = (size_t)(c0 + ty + 8*i) * 1024 + r0 + tx;
    dh[idx] = h; dl[idx] = lo;
  }
}

// ---------------- transpose + bf16 cast (MoE weights) ----------------
__global__ __launch_bounds__(256) void tcast_bf16_kernel(const float* __restrict__ src, unsigned short* __restrict__ dst,
                                                         int R, int C) {
  __shared__ float tile[32][33];
  size_t mo = (size_t)blockIdx.z * R * C;
  src += mo; dst += mo;
  int c0 = blockIdx.x * 32, r0 = blockIdx.y * 32;
  int tx = threadIdx.x & 31, ty = threadIdx.x >> 5;
  #pragma unroll
  for (int i = 0; i < 4; i++) tile[ty + 8*i][tx] = src[(size_t)(r0 + ty + 8*i) * C + c0 + tx];
  __syncthreads();
  #pragma unroll
  for (int i = 0; i < 4; i++) dst[(size_t)(c0 + ty + 8*i) * R + r0 + tx] = f2bf(tile[tx][ty + 8*i]);
}

// ---------------- split-fp16 128x128 GEMM core, double-buffered 2-phase pipeline ----------------
// lsbuf: 2 x 16384 f16 (64 KB). Per buffer (bytes): Ah0@0 Ah1@4096 Al0@8192 Al1@12288
//                                                   Bh0@16384 Bh1@20480 Bl0@24576 Bl1@28672
__device__ inline void gemm128s(const _Float16* __restrict__ Ah, const _Float16* __restrict__ Al,
                                const _Float16* __restrict__ Bh, const _Float16* __restrict__ Bl,
                                int lda, int ldb, int K, int bm, int bn,
                                _Float16* lsbuf, f32x4 (&acc)[4][4], f32x4 (&accx)[4][4]) {
  const int tid = threadIdx.x, w = tid >> 6, l = tid & 63, lr = l & 15, lg = l >> 4;
  const int wr = (w >> 1) * 64, wc = (w & 1) * 64;
  int ca = (((tid & 3) ^ ((tid >> 3) & 3)) * 8);
  int ra0 = tid >> 2, ra1 = 64 + (tid >> 2);
  const _Float16* gA0 = Ah + (size_t)(bm + ra0) * lda + ca;
  const _Float16* gA1 = Ah + (size_t)(bm + ra1) * lda + ca;
  const _Float16* gA2 = Al + (size_t)(bm + ra0) * lda + ca;
  const _Float16* gA3 = Al + (size_t)(bm + ra1) * lda + ca;
  const _Float16* gB0 = Bh + (size_t)(bn + ra0) * ldb + ca;
  const _Float16* gB1 = Bh + (size_t)(bn + ra1) * ldb + ca;
  const _Float16* gB2 = Bl + (size_t)(bn + ra0) * ldb + ca;
  const _Float16* gB3 = Bl + (size_t)(bn + ra1) * ldb + ca;
  char* base = (char*)lsbuf;
  const int wo = w * 1024;
#define STAGE8(bb, ko) do { \
    gload_lds16(gA0 + (ko), (bb) + wo);         gload_lds16(gA1 + (ko), (bb) + 4096 + wo);  \
    gload_lds16(gA2 + (ko), (bb) + 8192 + wo);  gload_lds16(gA3 + (ko), (bb) + 12288 + wo); \
    gload_lds16(gB0 + (ko), (bb) + 16384 + wo); gload_lds16(gB1 + (ko), (bb) + 20480 + wo); \
    gload_lds16(gB2 + (ko), (bb) + 24576 + wo); gload_lds16(gB3 + (ko), (bb) + 28672 + wo); } while (0)
  STAGE8(base, 0);
  __syncthreads();
  const int swzB = ((lg ^ ((lr >> 1) & 3)) << 4);   // byte offset of swizzled 16B slot pair
  int cur = 0;
  for (int ko = 0; ko < K; ko += 32) {
    char* bR = base + cur * 32768;
    if (ko + 32 < K) STAGE8(base + (cur ^ 1) * 32768, ko + 32);  // in flight across MFMA
    f16x8 ah[4], al4[4], bh4[4], bl4[4];
    #pragma unroll
    for (int m = 0; m < 4; m++) {
      int roff = (wr + m * 16 + lr) * 64 + swzB;
      ah[m]  = *(const f16x8*)(bR + roff);
      al4[m] = *(const f16x8*)(bR + 8192 + roff);
    }
    #pragma unroll
    for (int n = 0; n < 4; n++) {
      int roff = (wc + n * 16 + lr) * 64 + swzB;
      bh4[n] = *(const f16x8*)(bR + 16384 + roff);
      bl4[n] = *(const f16x8*)(bR + 24576 + roff);
    }
    __builtin_amdgcn_s_setprio(1);
    #pragma unroll
    for (int m = 0; m < 4; m++)
      #pragma unroll
      for (int n = 0; n < 4; n++) {
        acc[m][n]  = __builtin_amdgcn_mfma_f32_16x16x32_f16(ah[m], bh4[n], acc[m][n], 0, 0, 0);
        accx[m][n] = __builtin_amdgcn_mfma_f32_16x16x32_f16(ah[m], bl4[n], accx[m][n], 0, 0, 0);
        accx[m][n] = __builtin_amdgcn_mfma_f32_16x16x32_f16(al4[m], bh4[n], accx[m][n], 0, 0, 0);
      }
    __builtin_amdgcn_s_setprio(0);
    __syncthreads();   // drains this iter's stage (post-MFMA) + releases bR for next stage
    cur ^= 1;
  }
#undef STAGE8
}

// ---------------- QKV GEMM -> q linear (pre-scaled), K/V^T in swizzled 2048-elem tiles ----------------
__global__ __launch_bounds__(256) void gemm_qkv_kernel(const _Float16* __restrict__ xh, const _Float16* __restrict__ xl,
                                                       const _Float16* __restrict__ Wh, const _Float16* __restrict__ Wl,
                                                       _Float16* __restrict__ qh, _Float16* __restrict__ ql,
                                                       _Float16* __restrict__ kh, _Float16* __restrict__ kl,
                                                       _Float16* __restrict__ vh, _Float16* __restrict__ vl) {
  __shared__ _Float16 ls[32768];
  f32x4 acc[4][4] = {}, accx[4][4] = {};
  int bid = blockIdx.x;
  int sw = (bid & 7) * 96 + (bid >> 3);        // bijective XCD swizzle (768 = 8*96)
  int bm = (sw & 31) * 128, bn = (sw >> 5) * 128;
  gemm128s(xh, xl, Wh, Wl, 1024, 1024, 1024, bm, bn, ls, acc, accx);
  const int tid = threadIdx.x, w = tid >> 6, l = tid & 63, lr = l & 15, lg = l >> 4;
  const int wr = (w >> 1) * 64, wc = (w & 1) * 64;
  #pragma unroll
  for (int m = 0; m < 4; m++) {
    int row0 = bm + wr + m * 16 + lg * 4;
    #pragma unroll
    for (int n = 0; n < 4; n++) {
      int col = bn + wc + n * 16 + lr;
      int mat = col >> 10;
      int c = col & 1023, h = c >> 6, d = c & 63;
      if (mat == 2) {
        int bb = row0 >> 11, ss = row0 & 2047;
        int tile = ss >> 5, kvs = ss & 31;
        f16x4 ph, pl;
        #pragma unroll
        for (int j = 0; j < 4; j++) {
          float v = acc[m][n][j] + accx[m][n][j] * INV_LO;
          _Float16 hh, ll; split16(v, hh, ll);
          ph[j] = hh; pl[j] = ll;
        }
        size_t base = ((size_t)(bb * N_HEADS + h) * 64 + tile) * 2048;
        int off = d * 32 + ((((kvs >> 3) ^ (d & 3)) << 3) | (kvs & 7));
        *(f16x4*)(vh + base + off) = ph;
        *(f16x4*)(vl + base + off) = pl;
      } else if (mat == 1) {
        #pragma unroll
        for (int j = 0; j < 4; j++) {
          float v = acc[m][n][j] + accx[m][n][j] * INV_LO;
          _Float16 hh, ll; split16(v, hh, ll);
          int t = row0 + j, bb = t >> 11, ss = t & 2047;
          int tile = ss >> 5, r = ss & 31;
          size_t base = ((size_t)(bb * N_HEADS + h) * 64 + tile) * 2048;
          int off = r * 64 + ((((d >> 3) ^ (r & 7)) << 3) | (d & 7));
          kh[base + off] = hh; kl[base + off] = ll;
        }
      } else {
        #pragma unroll
        for (int j = 0; j < 4; j++) {
          float v = (acc[m][n][j] + accx[m][n][j] * INV_LO) * QSCALE;
          _Float16 hh, ll; split16(v, hh, ll);
          int t = row0 + j, bb = t >> 11, ss = t & 2047;
          size_t idx = ((size_t)(bb * N_HEADS + h) * SEQ + ss) * 64 + d;
          qh[idx] = hh; ql[idx] = ll;
        }
      }
    }
  }
}

// ---------------- Flash attention: 64q block (4 waves x 16q), KVBLK=32, dbuf gload_lds staging ----------------
__global__ __launch_bounds__(256, 4) void flash_kernel(const _Float16* __restrict__ qhp, const _Float16* __restrict__ qlp,
                                                       const _Float16* __restrict__ khs, const _Float16* __restrict__ kls,
                                                       const _Float16* __restrict__ vhs, const _Float16* __restrict__ vls,
                                                       _Float16* __restrict__ oh, _Float16* __restrict__ ol) {
  __shared__ _Float16 lsKV[2][8192];      // per buf: Kh@0 Kl@2048 Vh@4096 Vl@6144 (f16 elems)
  __shared__ _Float16 lsP[4][2][512];     // per-wave P hi/lo, 16x32 swizzled (64B rows)
  int wgid = blockIdx.x;
  int xcd = wgid & 7, kk = wgid >> 3;
  int bh = xcd * 4 + (kk >> 5), qt = kk & 31;   // XCD-local heads: 4 heads x 1MB K/V = L2-resident
  int tid = threadIdx.x, w = tid >> 6, l = tid & 63, lr = l & 15, lg = l >> 4;
  int q0 = qt * 64 + w * 16;
  const _Float16* qhb = qhp + (size_t)bh * SEQ * 64;
  const _Float16* qlb = qlp + (size_t)bh * SEQ * 64;
  f16x8 qfh[2], qfl[2];
  #pragma unroll
  for (int ks = 0; ks < 2; ks++) {
    size_t idx = (size_t)(q0 + lr) * 64 + ks * 32 + lg * 8;
    qfh[ks] = *(const f16x8*)(qhb + idx);
    qfl[ks] = *(const f16x8*)(qlb + idx);
  }
  const _Float16* splane = (w == 0) ? khs : (w == 1) ? kls : (w == 2) ? vhs : vls;
  const _Float16* sbase = splane + (size_t)bh * 131072 + l * 8;

  f32x4 acc[4] = {}, accx[4] = {};
  float mst = -1e30f, lst = 0.f;

  {
    const _Float16* sp = sbase;
    _Float16* dd = &lsKV[0][w * 2048];
    gload_lds16(sp, dd); gload_lds16(sp + 512, dd + 512);
    gload_lds16(sp + 1024, dd + 1024); gload_lds16(sp + 1536, dd + 1536);
  }
  __syncthreads();

  for (int t = 0; t < 64; t++) {
    int bR = t & 1;
    if (t < 63) {                               // stage next tile into the other buffer
      const _Float16* sp = sbase + (size_t)(t + 1) * 2048;
      _Float16* dd = &lsKV[bR ^ 1][w * 2048];
      gload_lds16(sp, dd); gload_lds16(sp + 512, dd + 512);
      gload_lds16(sp + 1024, dd + 1024); gload_lds16(sp + 1536, dd + 1536);
    }
    char* bufB = (char*)&lsKV[bR][0];

    // ---- QK^T ----
    f32x4 s[2] = {}, sx[2] = {};
    #pragma unroll
    for (int ks = 0; ks < 2; ks++) {
      f16x8 kfh[2], kfl[2];
      #pragma unroll
      for (int m = 0; m < 2; m++) {
        int off = (m * 16 + lr) * 128 + (((ks * 4 + lg) ^ (lr & 7)) << 4);
        kfh[m] = *(const f16x8*)(bufB + off);
        kfl[m] = *(const f16x8*)(bufB + 4096 + off);
      }
      __builtin_amdgcn_s_setprio(1);
      #pragma unroll
      for (int m = 0; m < 2; m++) {
        s[m]  = __builtin_amdgcn_mfma_f32_16x16x32_f16(kfh[m], qfh[ks], s[m], 0, 0, 0);
        sx[m] = __builtin_amdgcn_mfma_f32_16x16x32_f16(kfh[m], qfl[ks], sx[m], 0, 0, 0);
        sx[m] = __builtin_amdgcn_mfma_f32_16x16x32_f16(kfl[m], qfh[ks], sx[m], 0, 0, 0);
      }
      __builtin_amdgcn_s_setprio(0);
    }

    // ---- softmax ----
    float tm = -3e38f;
    #pragma unroll
    for (int m = 0; m < 2; m++)
      #pragma unroll
      for (int j = 0; j < 4; j++) {
        s[m][j] += sx[m][j] * INV_LO;
        tm = fmaxf(tm, s[m][j]);
      }
    tm = fmaxf(tm, __shfl_xor(tm, 16));
    tm = fmaxf(tm, __shfl_xor(tm, 32));
    if (!__all(tm - mst <= DTHR)) {
      float mnew = fmaxf(mst, tm);
      float corr = exp2f(mst - mnew);
      #pragma unroll
      for (int m2 = 0; m2 < 4; m2++)
        #pragma unroll
        for (int j = 0; j < 4; j++) { acc[m2][j] *= corr; accx[m2][j] *= corr; }
      lst *= corr;
      mst = mnew;
    }
    float psum = 0.f;
    #pragma unroll
    for (int m = 0; m < 2; m++) {
      f16x4 ph, pl;
      #pragma unroll
      for (int j = 0; j < 4; j++) {
        float p = exp2f(s[m][j] - mst);
        psum += p;
        _Float16 hh, ll; split16(p, hh, ll);
        ph[j] = hh; pl[j] = ll;
      }
      int boff = lr * 64 + ((((m * 2 + (lg >> 1)) ^ (lr & 3)) << 4) | ((lg & 1) * 8));
      *(f16x4*)((char*)&lsP[w][0][0] + boff) = ph;
      *(f16x4*)((char*)&lsP[w][1][0] + boff) = pl;
    }
    psum += __shfl_xor(psum, 16);
    psum += __shfl_xor(psum, 32);
    lst += psum;

    // ---- PV ----
    int poff = lr * 64 + ((lg ^ (lr & 3)) << 4);
    f16x8 pfh = *(const f16x8*)((char*)&lsP[w][0][0] + poff);
    f16x8 pfl = *(const f16x8*)((char*)&lsP[w][1][0] + poff);
    __builtin_amdgcn_s_setprio(1);
    #pragma unroll
    for (int m2 = 0; m2 < 4; m2++) {
      int voff = (m2 * 16 + lr) * 64 + ((lg ^ (lr & 3)) << 4);
      f16x8 vfh = *(const f16x8*)(bufB + 8192 + voff);
      f16x8 vfl = *(const f16x8*)(bufB + 12288 + voff);
      acc[m2]  = __builtin_amdgcn_mfma_f32_16x16x32_f16(vfh, pfh, acc[m2], 0, 0, 0);
      accx[m2] = __builtin_amdgcn_mfma_f32_16x16x32_f16(vfh, pfl, accx[m2], 0, 0, 0);
      accx[m2] = __builtin_amdgcn_mfma_f32_16x16x32_f16(vfl, pfh, accx[m2], 0, 0, 0);
    }
    __builtin_amdgcn_s_setprio(0);
    __syncthreads();   // waves done with bufR; bufW loads drained -> ready next iter
  }

  float inv = 1.f / lst;
  int b = bh >> 4, h = bh & 15;
  int tkn = b * SEQ + q0 + lr;
  #pragma unroll
  for (int m2 = 0; m2 < 4; m2++) {
    f16x4 ph, pl;
    #pragma unroll
    for (int j = 0; j < 4; j++) {
      float o = (acc[m2][j] + accx[m2][j] * INV_LO) * inv;
      _Float16 hh, ll; split16(o, hh, ll);
      ph[j] = hh; pl[j] = ll;
    }
    size_t idx = (size_t)tkn * D_MODEL + h * 64 + m2 * 16 + lg * 4;
    *(f16x4*)(oh + idx) = ph;
    *(f16x4*)(ol + idx) = pl;
  }
}

// ---------------- O-proj GEMM + residual -> d_out (fp32) ----------------
__global__ __launch_bounds__(256) void gemm_oproj_kernel(const _Float16* __restrict__ ah, const _Float16* __restrict__ al,
                                                         const _Float16* __restrict__ Wh, const _Float16* __restrict__ Wl,
                                                         const float* __restrict__ x, float* __restrict__ out) {
  __shared__ _Float16 ls[32768];
  f32x4 acc[4][4] = {}, accx[4][4] = {};
  int bid = blockIdx.x;
  int sw = (bid & 7) * 32 + (bid >> 3);        // bijective XCD swizzle (256 = 8*32)
  int bm = (sw & 31) * 128, bn = (sw >> 5) * 128;
  gemm128s(ah, al, Wh, Wl, 1024, 1024, 1024, bm, bn, ls, acc, accx);
  const int tid = threadIdx.x, w = tid >> 6, l = tid & 63, lr = l & 15, lg = l >> 4;
  const int wr = (w >> 1) * 64, wc = (w & 1) * 64;
  #pragma unroll
  for (int m = 0; m < 4; m++) {
    int row0 = bm + wr + m * 16 + lg * 4;
    #pragma unroll
    for (int n = 0; n < 4; n++) {
      int col = bn + wc + n * 16 + lr;
      #pragma unroll
      for (int j = 0; j < 4; j++) {
        size_t idx = (size_t)(row0 + j) * D_MODEL + col;
        out[idx] = (acc[m][n][j] + accx[m][n][j] * INV_LO) + x[idx];
      }
    }
  }
}

// ---------------- fused LN2 + xn2(bf16) + gate + top2 (fp32) ----------------
__global__ __launch_bounds__(256) void gate_kernel(const float* __restrict__ x1, const float* __restrict__ Wg,
                                                   const float* __restrict__ g2, const float* __restrict__ b2,
                                                   unsigned short* __restrict__ xn2,
                                                   int* __restrict__ cnt, int* __restrict__ topi,
                                                   float* __restrict__ topw) {
  int t = blockIdx.x * 4 + (threadIdx.x >> 6);
  int l = threadIdx.x & 63;
  const float* row = x1 + (size_t)t * D_MODEL;
  fx4 v[4];
  float s = 0.f, s2 = 0.f;
  #pragma unroll
  for (int i = 0; i < 4; i++) {
    v[i] = *(const fx4*)(row + l * 16 + i * 4);
    #pragma unroll
    for (int c = 0; c < 4; c++) { s += v[i][c]; s2 += v[i][c] * v[i][c]; }
  }
  #pragma unroll
  for (int off = 1; off < 64; off <<= 1) { s += __shfl_xor(s, off); s2 += __shfl_xor(s2, off); }
  float mu = s * (1.f / 1024.f);
  float var = s2 * (1.f / 1024.f) - mu * mu;
  float rstd = rsqrtf(var + 1e-5f);
  float a8[8] = {0,0,0,0,0,0,0,0};
  #pragma unroll
  for (int i = 0; i < 4; i++) {
    u16x4 ox;
    #pragma unroll
    for (int c = 0; c < 4; c++) {
      int kk = l * 16 + i * 4 + c;
      float xv = (v[i][c] - mu) * rstd * g2[kk] + b2[kk];
      ox[c] = f2bf(xv);
      const float* wr_ = Wg + (size_t)kk * 8;
      fx4 wa = *(const fx4*)wr_;
      fx4 wb = *(const fx4*)(wr_ + 4);
      a8[0] += xv * wa[0]; a8[1] += xv * wa[1]; a8[2] += xv * wa[2]; a8[3] += xv * wa[3];
      a8[4] += xv * wb[0]; a8[5] += xv * wb[1]; a8[6] += xv * wb[2]; a8[7] += xv * wb[3];
    }
    *(u16x4*)(xn2 + (size_t)t * D_MODEL + l * 16 + i * 4) = ox;
  }
  #pragma unroll
  for (int e = 0; e < 8; e++)
    #pragma unroll
    for (int off = 1; off < 64; off <<= 1) a8[e] += __shfl_xor(a8[e], off);
  if (l == 0) {
    int i0 = 0; float v0 = a8[0];
    #pragma unroll
    for (int e = 1; e < 8; e++) if (a8[e] > v0) { v0 = a8[e]; i0 = e; }
    int i1 = -1; float v1 = -3.4e38f;
    #pragma unroll
    for (int e = 0; e < 8; e++) if (e != i0 && a8[e] > v1) { v1 = a8[e]; i1 = e; }
    float p0 = 1.f / (1.f + __expf(v1 - v0));
    topi[t * 2] = i0; topi[t * 2 + 1] = i1;
    topw[t * 2] = p0; topw[t * 2 + 1] = 1.f - p0;
    atomicAdd(&cnt[i0], 1); atomicAdd(&cnt[i1], 1);
  }
}

__global__ void init_kernel(int* cnt, int* perm) {
  int i = blockIdx.x * 256 + threadIdx.x;
  if (i < 8) cnt[i] = 0;
  if (i < 8448) perm[i] = 0;
}

__global__ void offsets_kernel(const int* __restrict__ cnt, int* __restrict__ poff) {
  if (threadIdx.x == 0) {
    int a = 0;
    for (int e = 0; e < 8; e++) { poff[e] = a; a += ((cnt[e] + 31) >> 5) << 5; }
  }
}

// stable partition of the 8192 (token,k) assignments by expert -> deterministic
__global__ __launch_bounds__(256) void scatter_kernel(const int* __restrict__ topi,
                                                      const int* __restrict__ poff, int* __restrict__ perm,
                                                      int* __restrict__ slot_of) {
  int e = blockIdx.x, tid = threadIdx.x;
  __shared__ int basesh;
  __shared__ int wsum[4];
  if (tid == 0) basesh = poff[e];
  __syncthreads();
  for (int seg = 0; seg < 8192; seg += 256) {
    int a = seg + tid;
    int match = (topi[a] == e) ? 1 : 0;
    unsigned long long bal = __ballot(match);
    int wl = tid & 63, wv = tid >> 6;
    int lanepre = __popcll(bal & ((1ULL << wl) - 1ULL));
    if (wl == 0) wsum[wv] = __popcll(bal);
    __syncthreads();
    int wpre = 0;
    for (int i = 0; i < wv; i++) wpre += wsum[i];
    int total = wsum[0] + wsum[1] + wsum[2] + wsum[3];
    if (match) {
      int pos = basesh + wpre + lanepre;
      perm[pos] = a >> 1;
      slot_of[a] = pos;
    }
    __syncthreads();
    if (tid == 0) basesh += total;
    __syncthreads();
  }
}

// ---------------- MoE FFN: 32-token tile, fused W1->relu->W2, writes y[slot][1024] ----------------
__global__ __launch_bounds__(256) void moe_ffn_kernel(const unsigned short* __restrict__ xn2,
                                                      const unsigned short* __restrict__ W1T,
                                                      const unsigned short* __restrict__ W2T,
                                                      const int* __restrict__ cnt, const int* __restrict__ poff,
                                                      const int* __restrict__ perm,
                                                      float* __restrict__ y) {
  int bid = blockIdx.x;
  int e = -1, lt = bid;
  for (int i = 0; i < 8; i++) {
    int nt = (cnt[i] + 31) >> 5;
    if (lt < nt) { e = i; break; }
    lt -= nt;
  }
  if (e < 0) return;
  int slot0 = poff[e] + lt * 32;

  __shared__ int t_sh[32];
  __shared__ unsigned short lsX[32 * 32];
  __shared__ unsigned short hsh[32 * 520];
  int tid = threadIdx.x, w = tid >> 6, l = tid & 63, lr = l & 15, lg = l >> 4;
  if (tid < 32) t_sh[tid] = perm[slot0 + tid];
  __syncthreads();

  int Xr = tid >> 2;
  int Xc = (((tid & 3) ^ ((tid >> 3) & 3)) * 8);
  const unsigned short* gX = xn2 + (size_t)(tid < 128 ? t_sh[Xr & 31] : 0) * D_MODEL + Xc;
  const unsigned short* W1e = W1T + (size_t)e * EHID * D_MODEL;
  const unsigned short* W2e = W2T + (size_t)e * D_MODEL * EHID;
  const int swz = ((lg ^ ((lr >> 1) & 3)) << 3);

  f32x4 acc[2][8] = {};
  for (int ko = 0; ko < D_MODEL; ko += 32) {
    if (tid < 128) gload_lds16(gX + ko, (char*)lsX + w * 1024);
    __syncthreads();
    bf16x8 a[2];
    #pragma unroll
    for (int m = 0; m < 2; m++) a[m] = *(const bf16x8*)(lsX + (m*16 + lr) * 32 + swz);
    #pragma unroll
    for (int n = 0; n < 8; n++) {
      bf16x8 bb = *(const bf16x8*)(W1e + (size_t)(w * 128 + n * 16 + lr) * D_MODEL + ko + lg * 8);
      #pragma unroll
      for (int m = 0; m < 2; m++)
        acc[m][n] = __builtin_amdgcn_mfma_f32_16x16x32_bf16(a[m], bb, acc[m][n], 0, 0, 0);
    }
    __syncthreads();
  }
  #pragma unroll
  for (int m = 0; m < 2; m++)
    #pragma unroll
    for (int n = 0; n < 8; n++)
      #pragma unroll
      for (int j = 0; j < 4; j++)
        hsh[(m*16 + lg*4 + j) * 520 + w * 128 + n * 16 + lr] = f2bf(fmaxf(acc[m][n][j], 0.f));
  __syncthreads();

  for (int p = 0; p < 2; p++) {
    f32x4 acc2[2][8] = {};
    for (int k2 = 0; k2 < EHID; k2 += 32) {
      bf16x8 a2[2];
      #pragma unroll
      for (int m = 0; m < 2; m++) a2[m] = *(const bf16x8*)(hsh + (m*16 + lr) * 520 + k2 + lg * 8);
      #pragma unroll
      for (int n = 0; n < 8; n++) {
        int ycol = w * 256 + p * 128 + n * 16 + lr;
        bf16x8 bb = *(const bf16x8*)(W2e + (size_t)ycol * EHID + k2 + lg * 8);
        #pragma unroll
        for (int m = 0; m < 2; m++)
          acc2[m][n] = __builtin_amdgcn_mfma_f32_16x16x32_bf16(a2[m], bb, acc2[m][n], 0, 0, 0);
      }
    }
    #pragma unroll
    for (int m = 0; m < 2; m++)
      #pragma unroll
      for (int j = 0; j < 4; j++) {
        int r = m * 16 + lg * 4 + j;
        #pragma unroll
        for (int n = 0; n < 8; n++)
          y[(size_t)(slot0 + r) * D_MODEL + w * 256 + p * 128 + n * 16 + lr] = acc2[m][n][j];
      }
  }
}

// ---------------- combine: out[t] += w0*y[s0] + w1*y[s1] ----------------
__global__ __launch_bounds__(256) void combine_kernel(const float* __restrict__ y, const int* __restrict__ slot_of,
                                                      const float* __restrict__ topw, float* __restrict__ out) {
  int t = blockIdx.x * 4 + (threadIdx.x >> 6);
  int l = threadIdx.x & 63;
  int s0 = slot_of[t * 2], s1 = slot_of[t * 2 + 1];
  float w0 = topw[t * 2], w1 = topw[t * 2 + 1];
  const float* y0 = y + (size_t)s0 * D_MODEL + l * 16;
  const float* y1 = y + (size_t)s1 * D_MODEL + l * 16;
  float* o = out + (size_t)t * D_MODEL + l * 16;
  #pragma unroll
  for (int i = 0; i < 4; i++) {
    fx4 av = *(const fx4*)(y0 + i * 4);
    fx4 bv = *(const fx4*)(y1 + i * 4);
    fx4 d = *(const fx4*)(o + i * 4);
    #pragma unroll
    for (int j = 0; j < 4; j++) d[j] += w0 * av[j] + w1 * bv[j];
    *(fx4*)(o + i * 4) = d;
  }
}

// ---------------- launcher ----------------
#define MB (1u << 20)
extern "C" void kernel_launch(void* const* d_in, const int* in_sizes, int n_in,
                              void* d_out, int out_size, void* d_ws, size_t ws_size,
                              hipStream_t stream) {
  const float* x  = (const float*)d_in[0];
  const float* Wq = (const float*)d_in[1];
  const float* Wk = (const float*)d_in[2];
  const float* Wv = (const float*)d_in[3];
  const float* Wo = (const float*)d_in[4];
  const float* g1 = (const float*)d_in[5];
  const float* b1 = (const float*)d_in[6];
  const float* g2 = (const float*)d_in[7];
  const float* b2 = (const float*)d_in[8];
  const float* Wg = (const float*)d_in[9];
  const float* W1 = (const float*)d_in[10];
  const float* W2 = (const float*)d_in[11];
  float* out = (float*)d_out;

  char* ws = (char*)d_ws;
  _Float16* xn1h = (_Float16*)(ws + 0*MB);     // later aliased as attn hi plane
  _Float16* xn1l = (_Float16*)(ws + 8*MB);     // later aliased as attn lo plane
  _Float16* Wqkh = (_Float16*)(ws + 16*MB);
  _Float16* Wqkl = (_Float16*)(ws + 22*MB);
  _Float16* Woh  = (_Float16*)(ws + 28*MB);
  _Float16* Wol  = (_Float16*)(ws + 30*MB);
  _Float16* qhb  = (_Float16*)(ws + 32*MB);
  _Float16* qlb  = (_Float16*)(ws + 40*MB);
  _Float16* khb  = (_Float16*)(ws + 48*MB);
  _Float16* klb  = (_Float16*)(ws + 56*MB);
  _Float16* vhb  = (_Float16*)(ws + 64*MB);
  _Float16* vlb  = (_Float16*)(ws + 72*MB);
  unsigned short* xn2 = (unsigned short*)(ws + 80*MB);
  unsigned short* W1T = (unsigned short*)(ws + 88*MB);
  unsigned short* W2T = (unsigned short*)(ws + 96*MB);
  char* misc = ws + 104*MB;
  int*   topi    = (int*)(misc);
  float* topw    = (float*)(misc + 32768);
  int*   slot_of = (int*)(misc + 65536);
  int*   cnt     = (int*)(misc + 98304);
  int*   poff    = (int*)(misc + 98336);
  int*   perm    = (int*)(misc + 98368);
  float* ybuf    = (float*)(ws + 32*MB);       // aliases q/k/v buffers (dead after flash)
  _Float16* attnh = xn1h;
  _Float16* attnl = xn1l;

  // weight prep + routing init
  tcast4_kernel<<<dim3(32, 32, 4), 256, 0, stream>>>(Wq, Wk, Wv, Wo, Wqkh, Wqkl, Woh, Wol);
  tcast_bf16_kernel<<<dim3(16, 32, 8), 256, 0, stream>>>(W1, W1T, 1024, 512);
  tcast_bf16_kernel<<<dim3(32, 16, 8), 256, 0, stream>>>(W2, W2T, 512, 1024);
  init_kernel<<<33, 256, 0, stream>>>(cnt, perm);

  // attention path (split fp16, ~fp32 accuracy)
  ln_f16s_kernel<<<TOKENS, 256, 0, stream>>>(x, g1, b1, xn1h, xn1l);
  gemm_qkv_kernel<<<768, 256, 0, stream>>>(xn1h, xn1l, Wqkh, Wqkl, qhb, qlb, khb, klb, vhb, vlb);
  flash_kernel<<<1024, 256, 0, stream>>>(qhb, qlb, khb, klb, vhb, vlb, attnh, attnl);
  gemm_oproj_kernel<<<256, 256, 0, stream>>>(attnh, attnl, Woh, Wol, x, out);

  // MoE path
  gate_kernel<<<1024, 256, 0, stream>>>(out, Wg, g2, b2, xn2, cnt, topi, topw);
  offsets_kernel<<<1, 64, 0, stream>>>(cnt, poff);
  scatter_kernel<<<8, 256, 0, stream>>>(topi, poff, perm, slot_of);
  moe_ffn_kernel<<<264, 256, 0, stream>>>(xn2, W1T, W2T, cnt, poff, perm, ybuf);
  combine_kernel<<<1024, 256, 0, stream>>>(ybuf, slot_of, topw, out);

  (void)in_sizes; (void)n_in; (void)out_size; (void)ws_size;
}

// Round 7
// 591.637 us; speedup vs baseline: 1.1919x; 1.0145x over previous
//
#include <hip/hip_runtime.h>

typedef __attribute__((ext_vector_type(8))) _Float16 f16x8;
typedef __attribute__((ext_vector_type(4))) _Float16 f16x4;
typedef __attribute__((ext_vector_type(8))) short bf16x8;
typedef __attribute__((ext_vector_type(4))) float f32x4;
typedef __attribute__((ext_vector_type(4))) unsigned short u16x4;
typedef __attribute__((ext_vector_type(4))) float fx4;

#define D_MODEL 1024
#define N_HEADS 16
#define SEQ 2048
#define TOKENS 4096
#define N_EXP 8
#define EHID 512
#define LO_S 2048.0f
#define INV_LO (1.0f / 2048.0f)
#define QSCALE 0.18033688011112043f   // 0.125 * log2(e) folded into Q
#define DTHR 11.0f                    // defer-max threshold (log2 domain): P <= 2^11

__device__ inline unsigned short f2bf(float f) {
  union { float f; unsigned u; } v; v.f = f;
  unsigned u = v.u;
  return (unsigned short)((u + 0x7FFFu + ((u >> 16) & 1u)) >> 16);
}

__device__ inline void split16(float v, _Float16& h, _Float16& l) {
  h = (_Float16)v;
  l = (_Float16)((v - (float)h) * LO_S);
}

__device__ inline void gload_lds16(const void* g, void* lds) {
  __builtin_amdgcn_global_load_lds((const __attribute__((address_space(1))) void*)g,
                                   (__attribute__((address_space(3))) void*)lds, 16, 0, 0);
}

// ---------------- LayerNorm -> split fp16 planes ----------------
__global__ __launch_bounds__(256) void ln_f16s_kernel(const float* __restrict__ x, const float* __restrict__ g,
                                                      const float* __restrict__ b,
                                                      _Float16* __restrict__ xh, _Float16* __restrict__ xl) {
  int t = blockIdx.x, tid = threadIdx.x;
  const float* row = x + (size_t)t * D_MODEL;
  fx4 v = *(const fx4*)(row + tid * 4);
  float s = v[0] + v[1] + v[2] + v[3];
  float s2 = v[0]*v[0] + v[1]*v[1] + v[2]*v[2] + v[3]*v[3];
  #pragma unroll
  for (int off = 1; off < 64; off <<= 1) { s += __shfl_xor(s, off); s2 += __shfl_xor(s2, off); }
  __shared__ float red[8];
  int wv = tid >> 6, wl = tid & 63;
  if (wl == 0) { red[wv] = s; red[4 + wv] = s2; }
  __syncthreads();
  s = red[0] + red[1] + red[2] + red[3];
  s2 = red[4] + red[5] + red[6] + red[7];
  float mu = s * (1.f / 1024.f);
  float var = s2 * (1.f / 1024.f) - mu * mu;
  float rstd = rsqrtf(var + 1e-5f);
  int kk = tid * 4;
  f16x4 oh, ol;
  #pragma unroll
  for (int c = 0; c < 4; c++) {
    float y = (v[c] - mu) * rstd * g[kk + c] + b[kk + c];
    _Float16 h, lo; split16(y, h, lo);
    oh[c] = h; ol[c] = lo;
  }
  *(f16x4*)(xh + (size_t)t * D_MODEL + kk) = oh;
  *(f16x4*)(xl + (size_t)t * D_MODEL + kk) = ol;
}

// ---------------- fused transpose + split-fp16 cast for Wq/Wk/Wv/Wo ----------------
__global__ __launch_bounds__(256) void tcast4_kernel(const float* __restrict__ s0, const float* __restrict__ s1,
                                                     const float* __restrict__ s2, const float* __restrict__ s3,
                                                     _Float16* __restrict__ qkvh, _Float16* __restrict__ qkvl,
                                                     _Float16* __restrict__ woh, _Float16* __restrict__ wol) {
  int z = blockIdx.z;
  const float* src = (z == 0) ? s0 : (z == 1) ? s1 : (z == 2) ? s2 : s3;
  _Float16* dh = (z < 3) ? qkvh + (size_t)z * 1048576 : woh;
  _Float16* dl = (z < 3) ? qkvl + (size_t)z * 1048576 : wol;
  __shared__ float tile[32][33];
  int c0 = blockIdx.x * 32, r0 = blockIdx.y * 32;
  int tx = threadIdx.x & 31, ty = threadIdx.x >> 5;
  #pragma unroll
  for (int i = 0; i < 4; i++) tile[ty + 8*i][tx] = src[(size_t)(r0 + ty + 8*i) * 1024 + c0 + tx];
  __syncthreads();
  #pragma unroll
  for (int i = 0; i < 4; i++) {
    float v = tile[tx][ty + 8*i];
    _Float16 h, lo; split16(v, h, lo);
    size_t idx = (size_t)(c0 + ty + 8*i) * 1024 + r0 + tx;
    dh[idx] = h; dl[idx] = lo;
  }
}

// ---------------- transpose + bf16 cast (MoE weights) ----------------
__global__ __launch_bounds__(256) void tcast_bf16_kernel(const float* __restrict__ src, unsigned short* __restrict__ dst,
                                                         int R, int C) {
  __shared__ float tile[32][33];
  size_t mo = (size_t)blockIdx.z * R * C;
  src += mo; dst += mo;
  int c0 = blockIdx.x * 32, r0 = blockIdx.y * 32;
  int tx = threadIdx.x & 31, ty = threadIdx.x >> 5;
  #pragma unroll
  for (int i = 0; i < 4; i++) tile[ty + 8*i][tx] = src[(size_t)(r0 + ty + 8*i) * C + c0 + tx];
  __syncthreads();
  #pragma unroll
  for (int i = 0; i < 4; i++) dst[(size_t)(c0 + ty + 8*i) * R + r0 + tx] = f2bf(tile[tx][ty + 8*i]);
}

// ---------------- split-fp16 128x128 GEMM core, double-buffered 2-phase pipeline ----------------
__device__ inline void gemm128s(const _Float16* __restrict__ Ah, const _Float16* __restrict__ Al,
                                const _Float16* __restrict__ Bh, const _Float16* __restrict__ Bl,
                                int lda, int ldb, int K, int bm, int bn,
                                _Float16* lsbuf, f32x4 (&acc)[4][4], f32x4 (&accx)[4][4]) {
  const int tid = threadIdx.x, w = tid >> 6, l = tid & 63, lr = l & 15, lg = l >> 4;
  const int wr = (w >> 1) * 64, wc = (w & 1) * 64;
  int ca = (((tid & 3) ^ ((tid >> 3) & 3)) * 8);
  int ra0 = tid >> 2, ra1 = 64 + (tid >> 2);
  const _Float16* gA0 = Ah + (size_t)(bm + ra0) * lda + ca;
  const _Float16* gA1 = Ah + (size_t)(bm + ra1) * lda + ca;
  const _Float16* gA2 = Al + (size_t)(bm + ra0) * lda + ca;
  const _Float16* gA3 = Al + (size_t)(bm + ra1) * lda + ca;
  const _Float16* gB0 = Bh + (size_t)(bn + ra0) * ldb + ca;
  const _Float16* gB1 = Bh + (size_t)(bn + ra1) * ldb + ca;
  const _Float16* gB2 = Bl + (size_t)(bn + ra0) * ldb + ca;
  const _Float16* gB3 = Bl + (size_t)(bn + ra1) * ldb + ca;
  char* base = (char*)lsbuf;
  const int wo = w * 1024;
#define STAGE8(bb, ko) do { \
    gload_lds16(gA0 + (ko), (bb) + wo);         gload_lds16(gA1 + (ko), (bb) + 4096 + wo);  \
    gload_lds16(gA2 + (ko), (bb) + 8192 + wo);  gload_lds16(gA3 + (ko), (bb) + 12288 + wo); \
    gload_lds16(gB0 + (ko), (bb) + 16384 + wo); gload_lds16(gB1 + (ko), (bb) + 20480 + wo); \
    gload_lds16(gB2 + (ko), (bb) + 24576 + wo); gload_lds16(gB3 + (ko), (bb) + 28672 + wo); } while (0)
  STAGE8(base, 0);
  __syncthreads();
  const int swzB = ((lg ^ ((lr >> 1) & 3)) << 4);   // byte offset of swizzled 16B slot pair
  int cur = 0;
  for (int ko = 0; ko < K; ko += 32) {
    char* bR = base + cur * 32768;
    if (ko + 32 < K) STAGE8(base + (cur ^ 1) * 32768, ko + 32);  // in flight across MFMA
    f16x8 ah[4], al4[4], bh4[4], bl4[4];
    #pragma unroll
    for (int m = 0; m < 4; m++) {
      int roff = (wr + m * 16 + lr) * 64 + swzB;
      ah[m]  = *(const f16x8*)(bR + roff);
      al4[m] = *(const f16x8*)(bR + 8192 + roff);
    }
    #pragma unroll
    for (int n = 0; n < 4; n++) {
      int roff = (wc + n * 16 + lr) * 64 + swzB;
      bh4[n] = *(const f16x8*)(bR + 16384 + roff);
      bl4[n] = *(const f16x8*)(bR + 24576 + roff);
    }
    __builtin_amdgcn_s_setprio(1);
    #pragma unroll
    for (int m = 0; m < 4; m++)
      #pragma unroll
      for (int n = 0; n < 4; n++) {
        acc[m][n]  = __builtin_amdgcn_mfma_f32_16x16x32_f16(ah[m], bh4[n], acc[m][n], 0, 0, 0);
        accx[m][n] = __builtin_amdgcn_mfma_f32_16x16x32_f16(ah[m], bl4[n], accx[m][n], 0, 0, 0);
        accx[m][n] = __builtin_amdgcn_mfma_f32_16x16x32_f16(al4[m], bh4[n], accx[m][n], 0, 0, 0);
      }
    __builtin_amdgcn_s_setprio(0);
    __syncthreads();   // drains this iter's stage (post-MFMA) + releases bR for next stage
    cur ^= 1;
  }
#undef STAGE8
}

// ---------------- QKV GEMM -> q linear (pre-scaled), K/V^T in swizzled 2048-elem tiles ----------------
// K tile: rows r (128B), elem (r,d) at r*64 + (((d>>3)^(r&7))<<3 | (d&7))         [8 slots, f=r&7]
// V tile: rows d (64B),  elem (d,kvs) at d*32 + (((kvs>>3)^((d>>1)&3))<<3 | (kvs&7)) [4 slots, f=(d>>1)&3]
__global__ __launch_bounds__(256) void gemm_qkv_kernel(const _Float16* __restrict__ xh, const _Float16* __restrict__ xl,
                                                       const _Float16* __restrict__ Wh, const _Float16* __restrict__ Wl,
                                                       _Float16* __restrict__ qh, _Float16* __restrict__ ql,
                                                       _Float16* __restrict__ kh, _Float16* __restrict__ kl,
                                                       _Float16* __restrict__ vh, _Float16* __restrict__ vl) {
  __shared__ _Float16 ls[32768];
  f32x4 acc[4][4] = {}, accx[4][4] = {};
  int bid = blockIdx.x;
  int sw = (bid & 7) * 96 + (bid >> 3);        // bijective XCD swizzle (768 = 8*96)
  int bm = (sw & 31) * 128, bn = (sw >> 5) * 128;
  gemm128s(xh, xl, Wh, Wl, 1024, 1024, 1024, bm, bn, ls, acc, accx);
  const int tid = threadIdx.x, w = tid >> 6, l = tid & 63, lr = l & 15, lg = l >> 4;
  const int wr = (w >> 1) * 64, wc = (w & 1) * 64;
  #pragma unroll
  for (int m = 0; m < 4; m++) {
    int row0 = bm + wr + m * 16 + lg * 4;
    #pragma unroll
    for (int n = 0; n < 4; n++) {
      int col = bn + wc + n * 16 + lr;
      int mat = col >> 10;
      int c = col & 1023, h = c >> 6, d = c & 63;
      if (mat == 2) {
        int bb = row0 >> 11, ss = row0 & 2047;
        int tile = ss >> 5, kvs = ss & 31;
        f16x4 ph, pl;
        #pragma unroll
        for (int j = 0; j < 4; j++) {
          float v = acc[m][n][j] + accx[m][n][j] * INV_LO;
          _Float16 hh, ll; split16(v, hh, ll);
          ph[j] = hh; pl[j] = ll;
        }
        size_t base = ((size_t)(bb * N_HEADS + h) * 64 + tile) * 2048;
        int off = d * 32 + ((((kvs >> 3) ^ ((d >> 1) & 3)) << 3) | (kvs & 7));
        *(f16x4*)(vh + base + off) = ph;
        *(f16x4*)(vl + base + off) = pl;
      } else if (mat == 1) {
        #pragma unroll
        for (int j = 0; j < 4; j++) {
          float v = acc[m][n][j] + accx[m][n][j] * INV_LO;
          _Float16 hh, ll; split16(v, hh, ll);
          int t = row0 + j, bb = t >> 11, ss = t & 2047;
          int tile = ss >> 5, r = ss & 31;
          size_t base = ((size_t)(bb * N_HEADS + h) * 64 + tile) * 2048;
          int off = r * 64 + ((((d >> 3) ^ (r & 7)) << 3) | (d & 7));
          kh[base + off] = hh; kl[base + off] = ll;
        }
      } else {
        #pragma unroll
        for (int j = 0; j < 4; j++) {
          float v = (acc[m][n][j] + accx[m][n][j] * INV_LO) * QSCALE;
          _Float16 hh, ll; split16(v, hh, ll);
          int t = row0 + j, bb = t >> 11, ss = t & 2047;
          size_t idx = ((size_t)(bb * N_HEADS + h) * SEQ + ss) * 64 + d;
          qh[idx] = hh; ql[idx] = ll;
        }
      }
    }
  }
}

// ---------------- Flash attention: 64q block (4 waves x 16q), KVBLK=32, dbuf gload_lds staging ----------------
__global__ __launch_bounds__(256, 4) void flash_kernel(const _Float16* __restrict__ qhp, const _Float16* __restrict__ qlp,
                                                       const _Float16* __restrict__ khs, const _Float16* __restrict__ kls,
                                                       const _Float16* __restrict__ vhs, const _Float16* __restrict__ vls,
                                                       _Float16* __restrict__ oh, _Float16* __restrict__ ol) {
  __shared__ _Float16 lsKV[2][8192];      // per buf: Kh@0 Kl@2048 Vh@4096 Vl@6144 (f16 elems)
  __shared__ _Float16 lsP[4][2][512];     // per-wave P hi/lo, 16x32 swizzled (64B rows)
  int wgid = blockIdx.x;
  int xcd = wgid & 7, kk = wgid >> 3;
  int bh = xcd * 4 + (kk >> 5), qt = kk & 31;   // XCD-local heads: 4 heads x 1MB K/V = L2-resident
  int tid = threadIdx.x, w = tid >> 6, l = tid & 63, lr = l & 15, lg = l >> 4;
  int q0 = qt * 64 + w * 16;
  const _Float16* qhb = qhp + (size_t)bh * SEQ * 64;
  const _Float16* qlb = qlp + (size_t)bh * SEQ * 64;
  f16x8 qfh[2], qfl[2];
  #pragma unroll
  for (int ks = 0; ks < 2; ks++) {
    size_t idx = (size_t)(q0 + lr) * 64 + ks * 32 + lg * 8;
    qfh[ks] = *(const f16x8*)(qhb + idx);
    qfl[ks] = *(const f16x8*)(qlb + idx);
  }
  const _Float16* splane = (w == 0) ? khs : (w == 1) ? kls : (w == 2) ? vhs : vls;
  const _Float16* sbase = splane + (size_t)bh * 131072 + l * 8;

  f32x4 acc[4] = {}, accx[4] = {};
  float mst = -1e30f, lst = 0.f;

  {
    const _Float16* sp = sbase;
    _Float16* dd = &lsKV[0][w * 2048];
    gload_lds16(sp, dd); gload_lds16(sp + 512, dd + 512);
    gload_lds16(sp + 1024, dd + 1024); gload_lds16(sp + 1536, dd + 1536);
  }
  __syncthreads();

  for (int t = 0; t < 64; t++) {
    int bR = t & 1;
    if (t < 63) {                               // stage next tile into the other buffer
      const _Float16* sp = sbase + (size_t)(t + 1) * 2048;
      _Float16* dd = &lsKV[bR ^ 1][w * 2048];
      gload_lds16(sp, dd); gload_lds16(sp + 512, dd + 512);
      gload_lds16(sp + 1024, dd + 1024); gload_lds16(sp + 1536, dd + 1536);
    }
    char* bufB = (char*)&lsKV[bR][0];

    // ---- QK^T ----
    f32x4 s[2] = {}, sx[2] = {};
    #pragma unroll
    for (int ks = 0; ks < 2; ks++) {
      f16x8 kfh[2], kfl[2];
      #pragma unroll
      for (int m = 0; m < 2; m++) {
        int off = (m * 16 + lr) * 128 + (((ks * 4 + lg) ^ (lr & 7)) << 4);
        kfh[m] = *(const f16x8*)(bufB + off);
        kfl[m] = *(const f16x8*)(bufB + 4096 + off);
      }
      __builtin_amdgcn_s_setprio(1);
      #pragma unroll
      for (int m = 0; m < 2; m++) {
        s[m]  = __builtin_amdgcn_mfma_f32_16x16x32_f16(kfh[m], qfh[ks], s[m], 0, 0, 0);
        sx[m] = __builtin_amdgcn_mfma_f32_16x16x32_f16(kfh[m], qfl[ks], sx[m], 0, 0, 0);
        sx[m] = __builtin_amdgcn_mfma_f32_16x16x32_f16(kfl[m], qfh[ks], sx[m], 0, 0, 0);
      }
      __builtin_amdgcn_s_setprio(0);
    }

    // ---- softmax ----
    float tm = -3e38f;
    #pragma unroll
    for (int m = 0; m < 2; m++)
      #pragma unroll
      for (int j = 0; j < 4; j++) {
        s[m][j] += sx[m][j] * INV_LO;
        tm = fmaxf(tm, s[m][j]);
      }
    tm = fmaxf(tm, __shfl_xor(tm, 16));
    tm = fmaxf(tm, __shfl_xor(tm, 32));
    if (!__all(tm - mst <= DTHR)) {
      float mnew = fmaxf(mst, tm);
      float corr = exp2f(mst - mnew);
      #pragma unroll
      for (int m2 = 0; m2 < 4; m2++)
        #pragma unroll
        for (int j = 0; j < 4; j++) { acc[m2][j] *= corr; accx[m2][j] *= corr; }
      lst *= corr;
      mst = mnew;
    }
    float psum = 0.f;
    #pragma unroll
    for (int m = 0; m < 2; m++) {
      f16x4 ph, pl;
      #pragma unroll
      for (int j = 0; j < 4; j++) {
        float p = exp2f(s[m][j] - mst);
        psum += p;
        _Float16 hh, ll; split16(p, hh, ll);
        ph[j] = hh; pl[j] = ll;
      }
      int boff = lr * 64 + ((((m * 2 + (lg >> 1)) ^ ((lr >> 1) & 3)) << 4) | ((lg & 1) * 8));
      *(f16x4*)((char*)&lsP[w][0][0] + boff) = ph;
      *(f16x4*)((char*)&lsP[w][1][0] + boff) = pl;
    }
    psum += __shfl_xor(psum, 16);
    psum += __shfl_xor(psum, 32);
    lst += psum;

    // ---- PV ----
    int poff = lr * 64 + ((lg ^ ((lr >> 1) & 3)) << 4);
    f16x8 pfh = *(const f16x8*)((char*)&lsP[w][0][0] + poff);
    f16x8 pfl = *(const f16x8*)((char*)&lsP[w][1][0] + poff);
    __builtin_amdgcn_s_setprio(1);
    #pragma unroll
    for (int m2 = 0; m2 < 4; m2++) {
      int voff = (m2 * 16 + lr) * 64 + ((lg ^ ((lr >> 1) & 3)) << 4);
      f16x8 vfh = *(const f16x8*)(bufB + 8192 + voff);
      f16x8 vfl = *(const f16x8*)(bufB + 12288 + voff);
      acc[m2]  = __builtin_amdgcn_mfma_f32_16x16x32_f16(vfh, pfh, acc[m2], 0, 0, 0);
      accx[m2] = __builtin_amdgcn_mfma_f32_16x16x32_f16(vfh, pfl, accx[m2], 0, 0, 0);
      accx[m2] = __builtin_amdgcn_mfma_f32_16x16x32_f16(vfl, pfh, accx[m2], 0, 0, 0);
    }
    __builtin_amdgcn_s_setprio(0);
    __syncthreads();   // waves done with bufR; bufW loads drained -> ready next iter
  }

  float inv = 1.f / lst;
  int b = bh >> 4, h = bh & 15;
  int tkn = b * SEQ + q0 + lr;
  #pragma unroll
  for (int m2 = 0; m2 < 4; m2++) {
    f16x4 ph, pl;
    #pragma unroll
    for (int j = 0; j < 4; j++) {
      float o = (acc[m2][j] + accx[m2][j] * INV_LO) * inv;
      _Float16 hh, ll; split16(o, hh, ll);
      ph[j] = hh; pl[j] = ll;
    }
    size_t idx = (size_t)tkn * D_MODEL + h * 64 + m2 * 16 + lg * 4;
    *(f16x4*)(oh + idx) = ph;
    *(f16x4*)(ol + idx) = pl;
  }
}

// ---------------- O-proj GEMM + residual -> d_out (fp32) ----------------
__global__ __launch_bounds__(256) void gemm_oproj_kernel(const _Float16* __restrict__ ah, const _Float16* __restrict__ al,
                                                         const _Float16* __restrict__ Wh, const _Float16* __restrict__ Wl,
                                                         const float* __restrict__ x, float* __restrict__ out) {
  __shared__ _Float16 ls[32768];
  f32x4 acc[4][4] = {}, accx[4][4] = {};
  int bid = blockIdx.x;
  int sw = (bid & 7) * 32 + (bid >> 3);        // bijective XCD swizzle (256 = 8*32)
  int bm = (sw & 31) * 128, bn = (sw >> 5) * 128;
  gemm128s(ah, al, Wh, Wl, 1024, 1024, 1024, bm, bn, ls, acc, accx);
  const int tid = threadIdx.x, w = tid >> 6, l = tid & 63, lr = l & 15, lg = l >> 4;
  const int wr = (w >> 1) * 64, wc = (w & 1) * 64;
  #pragma unroll
  for (int m = 0; m < 4; m++) {
    int row0 = bm + wr + m * 16 + lg * 4;
    #pragma unroll
    for (int n = 0; n < 4; n++) {
      int col = bn + wc + n * 16 + lr;
      #pragma unroll
      for (int j = 0; j < 4; j++) {
        size_t idx = (size_t)(row0 + j) * D_MODEL + col;
        out[idx] = (acc[m][n][j] + accx[m][n][j] * INV_LO) + x[idx];
      }
    }
  }
}

// ---------------- fused LN2 + xn2(bf16) + gate + top2 (fp32) ----------------
__global__ __launch_bounds__(256) void gate_kernel(const float* __restrict__ x1, const float* __restrict__ Wg,
                                                   const float* __restrict__ g2, const float* __restrict__ b2,
                                                   unsigned short* __restrict__ xn2,
                                                   int* __restrict__ cnt, int* __restrict__ topi,
                                                   float* __restrict__ topw) {
  int t = blockIdx.x * 4 + (threadIdx.x >> 6);
  int l = threadIdx.x & 63;
  const float* row = x1 + (size_t)t * D_MODEL;
  fx4 v[4];
  float s = 0.f, s2 = 0.f;
  #pragma unroll
  for (int i = 0; i < 4; i++) {
    v[i] = *(const fx4*)(row + l * 16 + i * 4);
    #pragma unroll
    for (int c = 0; c < 4; c++) { s += v[i][c]; s2 += v[i][c] * v[i][c]; }
  }
  #pragma unroll
  for (int off = 1; off < 64; off <<= 1) { s += __shfl_xor(s, off); s2 += __shfl_xor(s2, off); }
  float mu = s * (1.f / 1024.f);
  float var = s2 * (1.f / 1024.f) - mu * mu;
  float rstd = rsqrtf(var + 1e-5f);
  float a8[8] = {0,0,0,0,0,0,0,0};
  #pragma unroll
  for (int i = 0; i < 4; i++) {
    u16x4 ox;
    #pragma unroll
    for (int c = 0; c < 4; c++) {
      int kk = l * 16 + i * 4 + c;
      float xv = (v[i][c] - mu) * rstd * g2[kk] + b2[kk];
      ox[c] = f2bf(xv);
      const float* wr_ = Wg + (size_t)kk * 8;
      fx4 wa = *(const fx4*)wr_;
      fx4 wb = *(const fx4*)(wr_ + 4);
      a8[0] += xv * wa[0]; a8[1] += xv * wa[1]; a8[2] += xv * wa[2]; a8[3] += xv * wa[3];
      a8[4] += xv * wb[0]; a8[5] += xv * wb[1]; a8[6] += xv * wb[2]; a8[7] += xv * wb[3];
    }
    *(u16x4*)(xn2 + (size_t)t * D_MODEL + l * 16 + i * 4) = ox;
  }
  #pragma unroll
  for (int e = 0; e < 8; e++)
    #pragma unroll
    for (int off = 1; off < 64; off <<= 1) a8[e] += __shfl_xor(a8[e], off);
  if (l == 0) {
    int i0 = 0; float v0 = a8[0];
    #pragma unroll
    for (int e = 1; e < 8; e++) if (a8[e] > v0) { v0 = a8[e]; i0 = e; }
    int i1 = -1; float v1 = -3.4e38f;
    #pragma unroll
    for (int e = 0; e < 8; e++) if (e != i0 && a8[e] > v1) { v1 = a8[e]; i1 = e; }
    float p0 = 1.f / (1.f + __expf(v1 - v0));
    topi[t * 2] = i0; topi[t * 2 + 1] = i1;
    topw[t * 2] = p0; topw[t * 2 + 1] = 1.f - p0;
    atomicAdd(&cnt[i0], 1); atomicAdd(&cnt[i1], 1);
  }
}

__global__ void init_kernel(int* cnt, int* perm) {
  int i = blockIdx.x * 256 + threadIdx.x;
  if (i < 8) cnt[i] = 0;
  if (i < 8448) perm[i] = 0;
}

__global__ void offsets_kernel(const int* __restrict__ cnt, int* __restrict__ poff) {
  if (threadIdx.x == 0) {
    int a = 0;
    for (int e = 0; e < 8; e++) { poff[e] = a; a += ((cnt[e] + 31) >> 5) << 5; }
  }
}

// stable partition of the 8192 (token,k) assignments by expert -> deterministic
__global__ __launch_bounds__(256) void scatter_kernel(const int* __restrict__ topi,
                                                      const int* __restrict__ poff, int* __restrict__ perm,
                                                      int* __restrict__ slot_of) {
  int e = blockIdx.x, tid = threadIdx.x;
  __shared__ int basesh;
  __shared__ int wsum[4];
  if (tid == 0) basesh = poff[e];
  __syncthreads();
  for (int seg = 0; seg < 8192; seg += 256) {
    int a = seg + tid;
    int match = (topi[a] == e) ? 1 : 0;
    unsigned long long bal = __ballot(match);
    int wl = tid & 63, wv = tid >> 6;
    int lanepre = __popcll(bal & ((1ULL << wl) - 1ULL));
    if (wl == 0) wsum[wv] = __popcll(bal);
    __syncthreads();
    int wpre = 0;
    for (int i = 0; i < wv; i++) wpre += wsum[i];
    int total = wsum[0] + wsum[1] + wsum[2] + wsum[3];
    if (match) {
      int pos = basesh + wpre + lanepre;
      perm[pos] = a >> 1;
      slot_of[a] = pos;
    }
    __syncthreads();
    if (tid == 0) basesh += total;
    __syncthreads();
  }
}

// ---------------- MoE FFN: 32-token tile, fused W1->relu->W2, writes y[slot][1024] ----------------
__global__ __launch_bounds__(256) void moe_ffn_kernel(const unsigned short* __restrict__ xn2,
                                                      const unsigned short* __restrict__ W1T,
                                                      const unsigned short* __restrict__ W2T,
                                                      const int* __restrict__ cnt, const int* __restrict__ poff,
                                                      const int* __restrict__ perm,
                                                      float* __restrict__ y) {
  int bid = blockIdx.x;
  int e = -1, lt = bid;
  for (int i = 0; i < 8; i++) {
    int nt = (cnt[i] + 31) >> 5;
    if (lt < nt) { e = i; break; }
    lt -= nt;
  }
  if (e < 0) return;
  int slot0 = poff[e] + lt * 32;

  __shared__ int t_sh[32];
  __shared__ unsigned short lsX[32 * 32];
  __shared__ unsigned short hsh[32 * 520];
  int tid = threadIdx.x, w = tid >> 6, l = tid & 63, lr = l & 15, lg = l >> 4;
  if (tid < 32) t_sh[tid] = perm[slot0 + tid];
  __syncthreads();

  int Xr = tid >> 2;
  int Xc = (((tid & 3) ^ ((tid >> 3) & 3)) * 8);
  const unsigned short* gX = xn2 + (size_t)(tid < 128 ? t_sh[Xr & 31] : 0) * D_MODEL + Xc;
  const unsigned short* W1e = W1T + (size_t)e * EHID * D_MODEL;
  const unsigned short* W2e = W2T + (size_t)e * D_MODEL * EHID;
  const int swz = ((lg ^ ((lr >> 1) & 3)) << 3);

  f32x4 acc[2][8] = {};
  for (int ko = 0; ko < D_MODEL; ko += 32) {
    if (tid < 128) gload_lds16(gX + ko, (char*)lsX + w * 1024);
    __syncthreads();
    bf16x8 a[2];
    #pragma unroll
    for (int m = 0; m < 2; m++) a[m] = *(const bf16x8*)(lsX + (m*16 + lr) * 32 + swz);
    #pragma unroll
    for (int n = 0; n < 8; n++) {
      bf16x8 bb = *(const bf16x8*)(W1e + (size_t)(w * 128 + n * 16 + lr) * D_MODEL + ko + lg * 8);
      #pragma unroll
      for (int m = 0; m < 2; m++)
        acc[m][n] = __builtin_amdgcn_mfma_f32_16x16x32_bf16(a[m], bb, acc[m][n], 0, 0, 0);
    }
    __syncthreads();
  }
  #pragma unroll
  for (int m = 0; m < 2; m++)
    #pragma unroll
    for (int n = 0; n < 8; n++)
      #pragma unroll
      for (int j = 0; j < 4; j++)
        hsh[(m*16 + lg*4 + j) * 520 + w * 128 + n * 16 + lr] = f2bf(fmaxf(acc[m][n][j], 0.f));
  __syncthreads();

  for (int p = 0; p < 2; p++) {
    f32x4 acc2[2][8] = {};
    for (int k2 = 0; k2 < EHID; k2 += 32) {
      bf16x8 a2[2];
      #pragma unroll
      for (int m = 0; m < 2; m++) a2[m] = *(const bf16x8*)(hsh + (m*16 + lr) * 520 + k2 + lg * 8);
      #pragma unroll
      for (int n = 0; n < 8; n++) {
        int ycol = w * 256 + p * 128 + n * 16 + lr;
        bf16x8 bb = *(const bf16x8*)(W2e + (size_t)ycol * EHID + k2 + lg * 8);
        #pragma unroll
        for (int m = 0; m < 2; m++)
          acc2[m][n] = __builtin_amdgcn_mfma_f32_16x16x32_bf16(a2[m], bb, acc2[m][n], 0, 0, 0);
      }
    }
    #pragma unroll
    for (int m = 0; m < 2; m++)
      #pragma unroll
      for (int j = 0; j < 4; j++) {
        int r = m * 16 + lg * 4 + j;
        #pragma unroll
        for (int n = 0; n < 8; n++)
          y[(size_t)(slot0 + r) * D_MODEL + w * 256 + p * 128 + n * 16 + lr] = acc2[m][n][j];
      }
  }
}

// ---------------- combine: out[t] += w0*y[s0] + w1*y[s1] ----------------
__global__ __launch_bounds__(256) void combine_kernel(const float* __restrict__ y, const int* __restrict__ slot_of,
                                                      const float* __restrict__ topw, float* __restrict__ out) {
  int t = blockIdx.x * 4 + (threadIdx.x >> 6);
  int l = threadIdx.x & 63;
  int s0 = slot_of[t * 2], s1 = slot_of[t * 2 + 1];
  float w0 = topw[t * 2], w1 = topw[t * 2 + 1];
  const float* y0 = y + (size_t)s0 * D_MODEL + l * 16;
  const float* y1 = y + (size_t)s1 * D_MODEL + l * 16;
  float* o = out + (size_t)t * D_MODEL + l * 16;
  #pragma unroll
  for (int i = 0; i < 4; i++) {
    fx4 av = *(const fx4*)(y0 + i * 4);
    fx4 bv = *(const fx4*)(y1 + i * 4);
    fx4 d = *(const fx4*)(o + i * 4);
    #pragma unroll
    for (int j = 0; j < 4; j++) d[j] += w0 * av[j] + w1 * bv[j];
    *(fx4*)(o + i * 4) = d;
  }
}

// ---------------- launcher ----------------
#define MB (1u << 20)
extern "C" void kernel_launch(void* const* d_in, const int* in_sizes, int n_in,
                              void* d_out, int out_size, void* d_ws, size_t ws_size,
                              hipStream_t stream) {
  const float* x  = (const float*)d_in[0];
  const float* Wq = (const float*)d_in[1];
  const float* Wk = (const float*)d_in[2];
  const float* Wv = (const float*)d_in[3];
  const float* Wo = (const float*)d_in[4];
  const float* g1 = (const float*)d_in[5];
  const float* b1 = (const float*)d_in[6];
  const float* g2 = (const float*)d_in[7];
  const float* b2 = (const float*)d_in[8];
  const float* Wg = (const float*)d_in[9];
  const float* W1 = (const float*)d_in[10];
  const float* W2 = (const float*)d_in[11];
  float* out = (float*)d_out;

  char* ws = (char*)d_ws;
  _Float16* xn1h = (_Float16*)(ws + 0*MB);     // later aliased as attn hi plane
  _Float16* xn1l = (_Float16*)(ws + 8*MB);     // later aliased as attn lo plane
  _Float16* Wqkh = (_Float16*)(ws + 16*MB);
  _Float16* Wqkl = (_Float16*)(ws + 22*MB);
  _Float16* Woh  = (_Float16*)(ws + 28*MB);
  _Float16* Wol  = (_Float16*)(ws + 30*MB);
  _Float16* qhb  = (_Float16*)(ws + 32*MB);
  _Float16* qlb  = (_Float16*)(ws + 40*MB);
  _Float16* khb  = (_Float16*)(ws + 48*MB);
  _Float16* klb  = (_Float16*)(ws + 56*MB);
  _Float16* vhb  = (_Float16*)(ws + 64*MB);
  _Float16* vlb  = (_Float16*)(ws + 72*MB);
  unsigned short* xn2 = (unsigned short*)(ws + 80*MB);
  unsigned short* W1T = (unsigned short*)(ws + 88*MB);
  unsigned short* W2T = (unsigned short*)(ws + 96*MB);
  char* misc = ws + 104*MB;
  int*   topi    = (int*)(misc);
  float* topw    = (float*)(misc + 32768);
  int*   slot_of = (int*)(misc + 65536);
  int*   cnt     = (int*)(misc + 98304);
  int*   poff    = (int*)(misc + 98336);
  int*   perm    = (int*)(misc + 98368);
  float* ybuf    = (float*)(ws + 32*MB);       // aliases q/k/v buffers (dead after flash)
  _Float16* attnh = xn1h;
  _Float16* attnl = xn1l;

  // weight prep + routing init
  tcast4_kernel<<<dim3(32, 32, 4), 256, 0, stream>>>(Wq, Wk, Wv, Wo, Wqkh, Wqkl, Woh, Wol);
  tcast_bf16_kernel<<<dim3(16, 32, 8), 256, 0, stream>>>(W1, W1T, 1024, 512);
  tcast_bf16_kernel<<<dim3(32, 16, 8), 256, 0, stream>>>(W2, W2T, 512, 1024);
  init_kernel<<<33, 256, 0, stream>>>(cnt, perm);

  // attention path (split fp16, ~fp32 accuracy)
  ln_f16s_kernel<<<TOKENS, 256, 0, stream>>>(x, g1, b1, xn1h, xn1l);
  gemm_qkv_kernel<<<768, 256, 0, stream>>>(xn1h, xn1l, Wqkh, Wqkl, qhb, qlb, khb, klb, vhb, vlb);
  flash_kernel<<<1024, 256, 0, stream>>>(qhb, qlb, khb, klb, vhb, vlb, attnh, attnl);
  gemm_oproj_kernel<<<256, 256, 0, stream>>>(attnh, attnl, Woh, Wol, x, out);

  // MoE path
  gate_kernel<<<1024, 256, 0, stream>>>(out, Wg, g2, b2, xn2, cnt, topi, topw);
  offsets_kernel<<<1, 64, 0, stream>>>(cnt, poff);
  scatter_kernel<<<8, 256, 0, stream>>>(topi, poff, perm, slot_of);
  moe_ffn_kernel<<<264, 256, 0, stream>>>(xn2, W1T, W2T, cnt, poff, perm, ybuf);
  combine_kernel<<<1024, 256, 0, stream>>>(ybuf, slot_of, topw, out);

  (void)in_sizes; (void)n_in; (void)out_size; (void)ws_size;
}

// Round 9
// 529.726 us; speedup vs baseline: 1.3312x; 1.1169x over previous
//
#include <hip/hip_runtime.h>

typedef __attribute__((ext_vector_type(8))) _Float16 f16x8;
typedef __attribute__((ext_vector_type(4))) _Float16 f16x4;
typedef __attribute__((ext_vector_type(2))) _Float16 f16x2;
typedef __attribute__((ext_vector_type(2))) __fp16 fp16x2_n;
typedef __attribute__((ext_vector_type(8))) short bf16x8;
typedef __attribute__((ext_vector_type(4))) float f32x4;
typedef __attribute__((ext_vector_type(4))) unsigned short u16x4;
typedef __attribute__((ext_vector_type(4))) float fx4;

#define D_MODEL 1024
#define N_HEADS 16
#define SEQ 2048
#define TOKENS 4096
#define N_EXP 8
#define EHID 512
#define LO_S 2048.0f
#define INV_LO (1.0f / 2048.0f)
#define QSCALE 0.18033688011112043f   // 0.125 * log2(e) folded into Q
#define DTHR 11.0f                    // defer-max threshold (log2 domain): P <= 2^11

__device__ inline unsigned short f2bf(float f) {
  union { float f; unsigned u; } v; v.f = f;
  unsigned u = v.u;
  return (unsigned short)((u + 0x7FFFu + ((u >> 16) & 1u)) >> 16);
}

__device__ inline void split16(float v, _Float16& h, _Float16& l) {
  h = (_Float16)v;
  l = (_Float16)((v - (float)h) * LO_S);
}

__device__ inline void split2(float a, float b, f16x2& h, f16x2& l) {
  fp16x2_n hn = __builtin_amdgcn_cvt_pkrtz(a, b);
  h = __builtin_bit_cast(f16x2, hn);
  fp16x2_n ln = __builtin_amdgcn_cvt_pkrtz((a - (float)h[0]) * LO_S, (b - (float)h[1]) * LO_S);
  l = __builtin_bit_cast(f16x2, ln);
}

__device__ inline void gload_lds16(const void* g, void* lds) {
  __builtin_amdgcn_global_load_lds((const __attribute__((address_space(1))) void*)g,
                                   (__attribute__((address_space(3))) void*)lds, 16, 0, 0);
}

// ---------------- fused prep: all weight transposes + routing init ----------------
__global__ __launch_bounds__(256) void prep_kernel(const float* __restrict__ Wq, const float* __restrict__ Wk,
                                                   const float* __restrict__ Wv, const float* __restrict__ Wo,
                                                   const float* __restrict__ W1, const float* __restrict__ W2,
                                                   _Float16* __restrict__ qkvh, _Float16* __restrict__ qkvl,
                                                   _Float16* __restrict__ woh, _Float16* __restrict__ wol,
                                                   unsigned short* __restrict__ W1T, unsigned short* __restrict__ W2T,
                                                   int* __restrict__ cnt, int* __restrict__ perm) {
  int b = blockIdx.x;
  if (b >= 12288) {
    int i = (b - 12288) * 256 + threadIdx.x;
    if (i < 8) cnt[i] = 0;
    if (i < 8704) perm[i] = 0;
    return;
  }
  __shared__ float tile[32][33];
  int tx = threadIdx.x & 31, ty = threadIdx.x >> 5;
  if (b < 4096) {
    int z = b >> 10, rem = b & 1023;
    int c0 = (rem & 31) * 32, r0 = (rem >> 5) * 32;
    const float* src = (z == 0) ? Wq : (z == 1) ? Wk : (z == 2) ? Wv : Wo;
    _Float16* dh = (z < 3) ? qkvh + (size_t)z * 1048576 : woh;
    _Float16* dl = (z < 3) ? qkvl + (size_t)z * 1048576 : wol;
    #pragma unroll
    for (int i = 0; i < 4; i++) tile[ty + 8*i][tx] = src[(size_t)(r0 + ty + 8*i) * 1024 + c0 + tx];
    __syncthreads();
    #pragma unroll
    for (int i = 0; i < 4; i++) {
      float v = tile[tx][ty + 8*i];
      _Float16 h, lo; split16(v, h, lo);
      size_t idx = (size_t)(c0 + ty + 8*i) * 1024 + r0 + tx;
      dh[idx] = h; dl[idx] = lo;
    }
  } else if (b < 8192) {
    int q = b - 4096, z = q >> 9, rem = q & 511;
    int c0 = (rem & 15) * 32, r0 = (rem >> 4) * 32;       // R=1024, C=512
    const float* src = W1 + (size_t)z * 524288;
    unsigned short* dst = W1T + (size_t)z * 524288;
    #pragma unroll
    for (int i = 0; i < 4; i++) tile[ty + 8*i][tx] = src[(size_t)(r0 + ty + 8*i) * 512 + c0 + tx];
    __syncthreads();
    #pragma unroll
    for (int i = 0; i < 4; i++) dst[(size_t)(c0 + ty + 8*i) * 1024 + r0 + tx] = f2bf(tile[tx][ty + 8*i]);
  } else {
    int q = b - 8192, z = q >> 9, rem = q & 511;
    int c0 = (rem & 31) * 32, r0 = (rem >> 5) * 32;       // R=512, C=1024
    const float* src = W2 + (size_t)z * 524288;
    unsigned short* dst = W2T + (size_t)z * 524288;
    #pragma unroll
    for (int i = 0; i < 4; i++) tile[ty + 8*i][tx] = src[(size_t)(r0 + ty + 8*i) * 1024 + c0 + tx];
    __syncthreads();
    #pragma unroll
    for (int i = 0; i < 4; i++) dst[(size_t)(c0 + ty + 8*i) * 512 + r0 + tx] = f2bf(tile[tx][ty + 8*i]);
  }
}

// ---------------- LayerNorm -> split fp16 planes ----------------
__global__ __launch_bounds__(256) void ln_f16s_kernel(const float* __restrict__ x, const float* __restrict__ g,
                                                      const float* __restrict__ b,
                                                      _Float16* __restrict__ xh, _Float16* __restrict__ xl) {
  int t = blockIdx.x, tid = threadIdx.x;
  const float* row = x + (size_t)t * D_MODEL;
  fx4 v = *(const fx4*)(row + tid * 4);
  float s = v[0] + v[1] + v[2] + v[3];
  float s2 = v[0]*v[0] + v[1]*v[1] + v[2]*v[2] + v[3]*v[3];
  #pragma unroll
  for (int off = 1; off < 64; off <<= 1) { s += __shfl_xor(s, off); s2 += __shfl_xor(s2, off); }
  __shared__ float red[8];
  int wv = tid >> 6, wl = tid & 63;
  if (wl == 0) { red[wv] = s; red[4 + wv] = s2; }
  __syncthreads();
  s = red[0] + red[1] + red[2] + red[3];
  s2 = red[4] + red[5] + red[6] + red[7];
  float mu = s * (1.f / 1024.f);
  float var = s2 * (1.f / 1024.f) - mu * mu;
  float rstd = rsqrtf(var + 1e-5f);
  int kk = tid * 4;
  f16x4 oh, ol;
  #pragma unroll
  for (int c = 0; c < 4; c++) {
    float y = (v[c] - mu) * rstd * g[kk + c] + b[kk + c];
    _Float16 h, lo; split16(y, h, lo);
    oh[c] = h; ol[c] = lo;
  }
  *(f16x4*)(xh + (size_t)t * D_MODEL + kk) = oh;
  *(f16x4*)(xl + (size_t)t * D_MODEL + kk) = ol;
}

// ---------------- split-fp16 128x128 GEMM core, double-buffered 2-phase pipeline ----------------
__device__ inline void gemm128s(const _Float16* __restrict__ Ah, const _Float16* __restrict__ Al,
                                const _Float16* __restrict__ Bh, const _Float16* __restrict__ Bl,
                                int lda, int ldb, int K, int bm, int bn,
                                _Float16* lsbuf, f32x4 (&acc)[4][4], f32x4 (&accx)[4][4]) {
  const int tid = threadIdx.x, w = tid >> 6, l = tid & 63, lr = l & 15, lg = l >> 4;
  const int wr = (w >> 1) * 64, wc = (w & 1) * 64;
  int ca = (((tid & 3) ^ ((tid >> 3) & 3)) * 8);
  int ra0 = tid >> 2, ra1 = 64 + (tid >> 2);
  const _Float16* gA0 = Ah + (size_t)(bm + ra0) * lda + ca;
  const _Float16* gA1 = Ah + (size_t)(bm + ra1) * lda + ca;
  const _Float16* gA2 = Al + (size_t)(bm + ra0) * lda + ca;
  const _Float16* gA3 = Al + (size_t)(bm + ra1) * lda + ca;
  const _Float16* gB0 = Bh + (size_t)(bn + ra0) * ldb + ca;
  const _Float16* gB1 = Bh + (size_t)(bn + ra1) * ldb + ca;
  const _Float16* gB2 = Bl + (size_t)(bn + ra0) * ldb + ca;
  const _Float16* gB3 = Bl + (size_t)(bn + ra1) * ldb + ca;
  char* base = (char*)lsbuf;
  const int wo = w * 1024;
#define STAGE8(bb, ko) do { \
    gload_lds16(gA0 + (ko), (bb) + wo);         gload_lds16(gA1 + (ko), (bb) + 4096 + wo);  \
    gload_lds16(gA2 + (ko), (bb) + 8192 + wo);  gload_lds16(gA3 + (ko), (bb) + 12288 + wo); \
    gload_lds16(gB0 + (ko), (bb) + 16384 + wo); gload_lds16(gB1 + (ko), (bb) + 20480 + wo); \
    gload_lds16(gB2 + (ko), (bb) + 24576 + wo); gload_lds16(gB3 + (ko), (bb) + 28672 + wo); } while (0)
  STAGE8(base, 0);
  __syncthreads();
  const int swzB = ((lg ^ ((lr >> 1) & 3)) << 4);
  int cur = 0;
  for (int ko = 0; ko < K; ko += 32) {
    char* bR = base + cur * 32768;
    if (ko + 32 < K) STAGE8(base + (cur ^ 1) * 32768, ko + 32);
    f16x8 ah[4], al4[4], bh4[4], bl4[4];
    #pragma unroll
    for (int m = 0; m < 4; m++) {
      int roff = (wr + m * 16 + lr) * 64 + swzB;
      ah[m]  = *(const f16x8*)(bR + roff);
      al4[m] = *(const f16x8*)(bR + 8192 + roff);
    }
    #pragma unroll
    for (int n = 0; n < 4; n++) {
      int roff = (wc + n * 16 + lr) * 64 + swzB;
      bh4[n] = *(const f16x8*)(bR + 16384 + roff);
      bl4[n] = *(const f16x8*)(bR + 24576 + roff);
    }
    __builtin_amdgcn_s_setprio(1);
    #pragma unroll
    for (int m = 0; m < 4; m++)
      #pragma unroll
      for (int n = 0; n < 4; n++) {
        acc[m][n]  = __builtin_amdgcn_mfma_f32_16x16x32_f16(ah[m], bh4[n], acc[m][n], 0, 0, 0);
        accx[m][n] = __builtin_amdgcn_mfma_f32_16x16x32_f16(ah[m], bl4[n], accx[m][n], 0, 0, 0);
        accx[m][n] = __builtin_amdgcn_mfma_f32_16x16x32_f16(al4[m], bh4[n], accx[m][n], 0, 0, 0);
      }
    __builtin_amdgcn_s_setprio(0);
    __syncthreads();
    cur ^= 1;
  }
#undef STAGE8
}

// ---------------- QKV GEMM -> q linear (pre-scaled), K/V^T in swizzled 2048-elem tiles ----------------
__global__ __launch_bounds__(256) void gemm_qkv_kernel(const _Float16* __restrict__ xh, const _Float16* __restrict__ xl,
                                                       const _Float16* __restrict__ Wh, const _Float16* __restrict__ Wl,
                                                       _Float16* __restrict__ qh, _Float16* __restrict__ ql,
                                                       _Float16* __restrict__ kh, _Float16* __restrict__ kl,
                                                       _Float16* __restrict__ vh, _Float16* __restrict__ vl) {
  __shared__ _Float16 ls[32768];
  f32x4 acc[4][4] = {}, accx[4][4] = {};
  int bid = blockIdx.x;
  int sw = (bid & 7) * 96 + (bid >> 3);
  int bm = (sw & 31) * 128, bn = (sw >> 5) * 128;
  gemm128s(xh, xl, Wh, Wl, 1024, 1024, 1024, bm, bn, ls, acc, accx);
  const int tid = threadIdx.x, w = tid >> 6, l = tid & 63, lr = l & 15, lg = l >> 4;
  const int wr = (w >> 1) * 64, wc = (w & 1) * 64;
  #pragma unroll
  for (int m = 0; m < 4; m++) {
    int row0 = bm + wr + m * 16 + lg * 4;
    #pragma unroll
    for (int n = 0; n < 4; n++) {
      int col = bn + wc + n * 16 + lr;
      int mat = col >> 10;
      int c = col & 1023, h = c >> 6, d = c & 63;
      if (mat == 2) {
        int bb = row0 >> 11, ss = row0 & 2047;
        int tile = ss >> 5, kvs = ss & 31;
        f16x4 ph, pl;
        #pragma unroll
        for (int j = 0; j < 4; j++) {
          float v = acc[m][n][j] + accx[m][n][j] * INV_LO;
          _Float16 hh, ll; split16(v, hh, ll);
          ph[j] = hh; pl[j] = ll;
        }
        size_t base = ((size_t)(bb * N_HEADS + h) * 64 + tile) * 2048;
        int off = d * 32 + ((((kvs >> 3) ^ ((d >> 1) & 3)) << 3) | (kvs & 7));
        *(f16x4*)(vh + base + off) = ph;
        *(f16x4*)(vl + base + off) = pl;
      } else if (mat == 1) {
        #pragma unroll
        for (int j = 0; j < 4; j++) {
          float v = acc[m][n][j] + accx[m][n][j] * INV_LO;
          _Float16 hh, ll; split16(v, hh, ll);
          int t = row0 + j, bb = t >> 11, ss = t & 2047;
          int tile = ss >> 5, r = ss & 31;
          size_t base = ((size_t)(bb * N_HEADS + h) * 64 + tile) * 2048;
          int off = r * 64 + ((((d >> 3) ^ (r & 7)) << 3) | (d & 7));
          kh[base + off] = hh; kl[base + off] = ll;
        }
      } else {
        #pragma unroll
        for (int j = 0; j < 4; j++) {
          float v = (acc[m][n][j] + accx[m][n][j] * INV_LO) * QSCALE;
          _Float16 hh, ll; split16(v, hh, ll);
          int t = row0 + j, bb = t >> 11, ss = t & 2047;
          size_t idx = ((size_t)(bb * N_HEADS + h) * SEQ + ss) * 64 + d;
          qh[idx] = hh; ql[idx] = ll;
        }
      }
    }
  }
}

// ---------------- Flash attention: 64q block (4 waves x 16q), KVBLK=32, dbuf gload_lds staging ----------------
__global__ __launch_bounds__(256, 4) void flash_kernel(const _Float16* __restrict__ qhp, const _Float16* __restrict__ qlp,
                                                       const _Float16* __restrict__ khs, const _Float16* __restrict__ kls,
                                                       const _Float16* __restrict__ vhs, const _Float16* __restrict__ vls,
                                                       _Float16* __restrict__ oh, _Float16* __restrict__ ol) {
  __shared__ _Float16 lsKV[2][8192];
  __shared__ _Float16 lsP[4][2][512];
  int wgid = blockIdx.x;
  int xcd = wgid & 7, kk = wgid >> 3;
  int bh = xcd * 4 + (kk >> 5), qt = kk & 31;
  int tid = threadIdx.x, w = tid >> 6, l = tid & 63, lr = l & 15, lg = l >> 4;
  int q0 = qt * 64 + w * 16;
  const _Float16* qhb = qhp + (size_t)bh * SEQ * 64;
  const _Float16* qlb = qlp + (size_t)bh * SEQ * 64;
  f16x8 qfh[2], qfl[2];
  #pragma unroll
  for (int ks = 0; ks < 2; ks++) {
    size_t idx = (size_t)(q0 + lr) * 64 + ks * 32 + lg * 8;
    qfh[ks] = *(const f16x8*)(qhb + idx);
    qfl[ks] = *(const f16x8*)(qlb + idx);
  }
  const _Float16* splane = (w == 0) ? khs : (w == 1) ? kls : (w == 2) ? vhs : vls;
  const _Float16* sbase = splane + (size_t)bh * 131072 + l * 8;

  f32x4 acc[4] = {}, accx[4] = {};
  float mst = -1e30f, lstp = 0.f;

  {
    const _Float16* sp = sbase;
    _Float16* dd = &lsKV[0][w * 2048];
    gload_lds16(sp, dd); gload_lds16(sp + 512, dd + 512);
    gload_lds16(sp + 1024, dd + 1024); gload_lds16(sp + 1536, dd + 1536);
  }
  __syncthreads();

  for (int t = 0; t < 64; t++) {
    int bR = t & 1;
    if (t < 63) {
      const _Float16* sp = sbase + (size_t)(t + 1) * 2048;
      _Float16* dd = &lsKV[bR ^ 1][w * 2048];
      gload_lds16(sp, dd); gload_lds16(sp + 512, dd + 512);
      gload_lds16(sp + 1024, dd + 1024); gload_lds16(sp + 1536, dd + 1536);
    }
    char* bufB = (char*)&lsKV[bR][0];

    // ---- QK^T ----
    f32x4 s[2] = {}, sx[2] = {};
    #pragma unroll
    for (int ks = 0; ks < 2; ks++) {
      f16x8 kfh[2], kfl[2];
      #pragma unroll
      for (int m = 0; m < 2; m++) {
        int off = (m * 16 + lr) * 128 + (((ks * 4 + lg) ^ (lr & 7)) << 4);
        kfh[m] = *(const f16x8*)(bufB + off);
        kfl[m] = *(const f16x8*)(bufB + 4096 + off);
      }
      __builtin_amdgcn_s_setprio(1);
      #pragma unroll
      for (int m = 0; m < 2; m++) {
        s[m]  = __builtin_amdgcn_mfma_f32_16x16x32_f16(kfh[m], qfh[ks], s[m], 0, 0, 0);
        sx[m] = __builtin_amdgcn_mfma_f32_16x16x32_f16(kfh[m], qfl[ks], sx[m], 0, 0, 0);
        sx[m] = __builtin_amdgcn_mfma_f32_16x16x32_f16(kfl[m], qfh[ks], sx[m], 0, 0, 0);
      }
      __builtin_amdgcn_s_setprio(0);
    }

    // ---- softmax (per-lane defer check; deferred l-reduction) ----
    float tm = -3e38f;
    #pragma unroll
    for (int m = 0; m < 2; m++)
      #pragma unroll
      for (int j = 0; j < 4; j++) {
        s[m][j] += sx[m][j] * INV_LO;
        tm = fmaxf(tm, s[m][j]);
      }
    if (!__all(tm - mst <= DTHR)) {
      tm = fmaxf(tm, __shfl_xor(tm, 16));
      tm = fmaxf(tm, __shfl_xor(tm, 32));
      float mnew = fmaxf(mst, tm);
      float corr = exp2f(mst - mnew);
      #pragma unroll
      for (int m2 = 0; m2 < 4; m2++)
        #pragma unroll
        for (int j = 0; j < 4; j++) { acc[m2][j] *= corr; accx[m2][j] *= corr; }
      lstp *= corr;
      mst = mnew;
    }
    #pragma unroll
    for (int m = 0; m < 2; m++) {
      #pragma unroll
      for (int j = 0; j < 4; j++) {
        float p = exp2f(s[m][j] - mst);
        lstp += p;
        s[m][j] = p;
      }
      f16x2 h01, h23, l01, l23;
      split2(s[m][0], s[m][1], h01, l01);
      split2(s[m][2], s[m][3], h23, l23);
      f16x4 ph, pl;
      ph[0] = h01[0]; ph[1] = h01[1]; ph[2] = h23[0]; ph[3] = h23[1];
      pl[0] = l01[0]; pl[1] = l01[1]; pl[2] = l23[0]; pl[3] = l23[1];
      int boff = lr * 64 + ((((m * 2 + (lg >> 1)) ^ ((lr >> 1) & 3)) << 4) | ((lg & 1) * 8));
      *(f16x4*)((char*)&lsP[w][0][0] + boff) = ph;
      *(f16x4*)((char*)&lsP[w][1][0] + boff) = pl;
    }

    // ---- PV ----
    int poff = lr * 64 + ((lg ^ ((lr >> 1) & 3)) << 4);
    f16x8 pfh = *(const f16x8*)((char*)&lsP[w][0][0] + poff);
    f16x8 pfl = *(const f16x8*)((char*)&lsP[w][1][0] + poff);
    __builtin_amdgcn_s_setprio(1);
    #pragma unroll
    for (int m2 = 0; m2 < 4; m2++) {
      int voff = (m2 * 16 + lr) * 64 + ((lg ^ ((lr >> 1) & 3)) << 4);
      f16x8 vfh = *(const f16x8*)(bufB + 8192 + voff);
      f16x8 vfl = *(const f16x8*)(bufB + 12288 + voff);
      acc[m2]  = __builtin_amdgcn_mfma_f32_16x16x32_f16(vfh, pfh, acc[m2], 0, 0, 0);
      accx[m2] = __builtin_amdgcn_mfma_f32_16x16x32_f16(vfh, pfl, accx[m2], 0, 0, 0);
      accx[m2] = __builtin_amdgcn_mfma_f32_16x16x32_f16(vfl, pfh, accx[m2], 0, 0, 0);
    }
    __builtin_amdgcn_s_setprio(0);
    __syncthreads();
  }

  float lst = lstp + __shfl_xor(lstp, 16);
  lst += __shfl_xor(lst, 32);
  float inv = 1.f / lst;
  int b = bh >> 4, h = bh & 15;
  int tkn = b * SEQ + q0 + lr;
  #pragma unroll
  for (int m2 = 0; m2 < 4; m2++) {
    f16x4 ph, pl;
    #pragma unroll
    for (int j = 0; j < 4; j++) {
      float o = (acc[m2][j] + accx[m2][j] * INV_LO) * inv;
      _Float16 hh, ll; split16(o, hh, ll);
      ph[j] = hh; pl[j] = ll;
    }
    size_t idx = (size_t)tkn * D_MODEL + h * 64 + m2 * 16 + lg * 4;
    *(f16x4*)(oh + idx) = ph;
    *(f16x4*)(ol + idx) = pl;
  }
}

// ---------------- O-proj GEMM + residual -> d_out (fp32) ----------------
__global__ __launch_bounds__(256) void gemm_oproj_kernel(const _Float16* __restrict__ ah, const _Float16* __restrict__ al,
                                                         const _Float16* __restrict__ Wh, const _Float16* __restrict__ Wl,
                                                         const float* __restrict__ x, float* __restrict__ out) {
  __shared__ _Float16 ls[32768];
  f32x4 acc[4][4] = {}, accx[4][4] = {};
  int bid = blockIdx.x;
  int sw = (bid & 7) * 32 + (bid >> 3);
  int bm = (sw & 31) * 128, bn = (sw >> 5) * 128;
  gemm128s(ah, al, Wh, Wl, 1024, 1024, 1024, bm, bn, ls, acc, accx);
  const int tid = threadIdx.x, w = tid >> 6, l = tid & 63, lr = l & 15, lg = l >> 4;
  const int wr = (w >> 1) * 64, wc = (w & 1) * 64;
  #pragma unroll
  for (int m = 0; m < 4; m++) {
    int row0 = bm + wr + m * 16 + lg * 4;
    #pragma unroll
    for (int n = 0; n < 4; n++) {
      int col = bn + wc + n * 16 + lr;
      #pragma unroll
      for (int j = 0; j < 4; j++) {
        size_t idx = (size_t)(row0 + j) * D_MODEL + col;
        out[idx] = (acc[m][n][j] + accx[m][n][j] * INV_LO) + x[idx];
      }
    }
  }
}

// ---------------- fused LN2 + xn2(bf16) + gate + top2 (fp32) ----------------
__global__ __launch_bounds__(256) void gate_kernel(const float* __restrict__ x1, const float* __restrict__ Wg,
                                                   const float* __restrict__ g2, const float* __restrict__ b2,
                                                   unsigned short* __restrict__ xn2,
                                                   int* __restrict__ cnt, int* __restrict__ topi,
                                                   float* __restrict__ topw) {
  int t = blockIdx.x * 4 + (threadIdx.x >> 6);
  int l = threadIdx.x & 63;
  const float* row = x1 + (size_t)t * D_MODEL;
  fx4 v[4];
  float s = 0.f, s2 = 0.f;
  #pragma unroll
  for (int i = 0; i < 4; i++) {
    v[i] = *(const fx4*)(row + l * 16 + i * 4);
    #pragma unroll
    for (int c = 0; c < 4; c++) { s += v[i][c]; s2 += v[i][c] * v[i][c]; }
  }
  #pragma unroll
  for (int off = 1; off < 64; off <<= 1) { s += __shfl_xor(s, off); s2 += __shfl_xor(s2, off); }
  float mu = s * (1.f / 1024.f);
  float var = s2 * (1.f / 1024.f) - mu * mu;
  float rstd = rsqrtf(var + 1e-5f);
  float a8[8] = {0,0,0,0,0,0,0,0};
  #pragma unroll
  for (int i = 0; i < 4; i++) {
    u16x4 ox;
    #pragma unroll
    for (int c = 0; c < 4; c++) {
      int kk = l * 16 + i * 4 + c;
      float xv = (v[i][c] - mu) * rstd * g2[kk] + b2[kk];
      ox[c] = f2bf(xv);
      const float* wr_ = Wg + (size_t)kk * 8;
      fx4 wa = *(const fx4*)wr_;
      fx4 wb = *(const fx4*)(wr_ + 4);
      a8[0] += xv * wa[0]; a8[1] += xv * wa[1]; a8[2] += xv * wa[2]; a8[3] += xv * wa[3];
      a8[4] += xv * wb[0]; a8[5] += xv * wb[1]; a8[6] += xv * wb[2]; a8[7] += xv * wb[3];
    }
    *(u16x4*)(xn2 + (size_t)t * D_MODEL + l * 16 + i * 4) = ox;
  }
  #pragma unroll
  for (int e = 0; e < 8; e++)
    #pragma unroll
    for (int off = 1; off < 64; off <<= 1) a8[e] += __shfl_xor(a8[e], off);
  if (l == 0) {
    int i0 = 0; float v0 = a8[0];
    #pragma unroll
    for (int e = 1; e < 8; e++) if (a8[e] > v0) { v0 = a8[e]; i0 = e; }
    int i1 = -1; float v1 = -3.4e38f;
    #pragma unroll
    for (int e = 0; e < 8; e++) if (e != i0 && a8[e] > v1) { v1 = a8[e]; i1 = e; }
    float p0 = 1.f / (1.f + __expf(v1 - v0));
    topi[t * 2] = i0; topi[t * 2 + 1] = i1;
    topw[t * 2] = p0; topw[t * 2 + 1] = 1.f - p0;
    atomicAdd(&cnt[i0], 1); atomicAdd(&cnt[i1], 1);
  }
}

// stable partition of the 8192 (token,k) assignments by expert (64-granule slots)
__global__ __launch_bounds__(256) void scatter_kernel(const int* __restrict__ topi, const int* __restrict__ cnt,
                                                      int* __restrict__ perm, int* __restrict__ slot_of) {
  int e = blockIdx.x, tid = threadIdx.x;
  __shared__ int basesh;
  __shared__ int wsum[4];
  if (tid == 0) {
    int a = 0;
    for (int i = 0; i < e; i++) a += ((cnt[i] + 63) >> 6) << 6;
    basesh = a;
  }
  __syncthreads();
  for (int seg = 0; seg < 8192; seg += 256) {
    int a = seg + tid;
    int match = (topi[a] == e) ? 1 : 0;
    unsigned long long bal = __ballot(match);
    int wl = tid & 63, wv = tid >> 6;
    int lanepre = __popcll(bal & ((1ULL << wl) - 1ULL));
    if (wl == 0) wsum[wv] = __popcll(bal);
    __syncthreads();
    int wpre = 0;
    for (int i = 0; i < wv; i++) wpre += wsum[i];
    int total = wsum[0] + wsum[1] + wsum[2] + wsum[3];
    if (match) {
      int pos = basesh + wpre + lanepre;
      perm[pos] = a >> 1;
      slot_of[a] = pos;
    }
    __syncthreads();
    if (tid == 0) basesh += total;
    __syncthreads();
  }
}

// ---------------- MoE FFN: 64-token tile, 8 waves, hid in 2 halves, writes y[slot][1024] ----------------
__global__ __launch_bounds__(512) void moe_ffn_kernel(const unsigned short* __restrict__ xn2,
                                                      const unsigned short* __restrict__ W1T,
                                                      const unsigned short* __restrict__ W2T,
                                                      const int* __restrict__ cnt,
                                                      const int* __restrict__ perm,
                                                      float* __restrict__ y) {
  int bid = blockIdx.x;
  int e = -1, lt = bid, off = 0;
  for (int i = 0; i < 8; i++) {
    int nt = (cnt[i] + 63) >> 6;
    if (lt < nt) { e = i; break; }
    lt -= nt; off += nt << 6;
  }
  if (e < 0) return;
  int slot0 = off + lt * 64;

  __shared__ int t_sh[64];
  __shared__ unsigned short lsX[64 * 128];   // 16 KB, one K-chunk of 128
  __shared__ unsigned short hsh[64 * 264];   // 33.8 KB, half-hid h tile
  int tid = threadIdx.x, w = tid >> 6, l = tid & 63, lr = l & 15, lg = l >> 4;
  if (tid < 64) t_sh[tid] = perm[slot0 + tid];
  __syncthreads();

  const unsigned short* W1e = W1T + (size_t)e * EHID * D_MODEL;
  const unsigned short* W2e = W2T + (size_t)e * D_MODEL * EHID;

  f32x4 acc2[4][8] = {};   // persists across both hid halves: y cols w*128 + n*16 + lr
  for (int h = 0; h < 2; h++) {
    // ---- phase 1: h_half = relu(X @ W1[h*256..+256]) ----
    f32x4 acc1[4][2] = {};
    for (int kc = 0; kc < 8; kc++) {
      __syncthreads();
      #pragma unroll
      for (int L = 0; L < 2; L++) {
        int u = tid + 512 * L;
        int r = u >> 4, sp = u & 15;
        int cs = (sp & 8) | ((sp & 7) ^ (r & 7));
        gload_lds16(xn2 + (size_t)t_sh[r] * D_MODEL + kc * 128 + cs * 8, (char*)lsX + u * 16);
      }
      __syncthreads();
      #pragma unroll
      for (int kst = 0; kst < 4; kst++) {
        bf16x8 a[4];
        #pragma unroll
        for (int m = 0; m < 4; m++) {
          int row = m * 16 + lr;
          int slot = kst * 4 + lg;
          int cs = (slot & 8) | ((slot & 7) ^ (row & 7));
          a[m] = *(const bf16x8*)((char*)lsX + row * 256 + cs * 16);
        }
        int ko = kc * 128 + kst * 32;
        #pragma unroll
        for (int n = 0; n < 2; n++) {
          bf16x8 bb = *(const bf16x8*)(W1e + (size_t)(h * 256 + w * 32 + n * 16 + lr) * D_MODEL + ko + lg * 8);
          #pragma unroll
          for (int m = 0; m < 4; m++)
            acc1[m][n] = __builtin_amdgcn_mfma_f32_16x16x32_bf16(a[m], bb, acc1[m][n], 0, 0, 0);
        }
      }
    }
    __syncthreads();
    #pragma unroll
    for (int m = 0; m < 4; m++)
      #pragma unroll
      for (int n = 0; n < 2; n++)
        #pragma unroll
        for (int j = 0; j < 4; j++)
          hsh[(m*16 + lg*4 + j) * 264 + w * 32 + n * 16 + lr] = f2bf(fmaxf(acc1[m][n][j], 0.f));
    __syncthreads();
    // ---- phase 2 partial: acc2 += h_half @ W2[h*256..+256] (8 barrier-free K-steps) ----
    for (int k2 = 0; k2 < 256; k2 += 32) {
      bf16x8 a2[4];
      #pragma unroll
      for (int m = 0; m < 4; m++) a2[m] = *(const bf16x8*)(hsh + (m*16 + lr) * 264 + k2 + lg * 8);
      #pragma unroll
      for (int n = 0; n < 8; n++) {
        bf16x8 bb = *(const bf16x8*)(W2e + (size_t)(w * 128 + n * 16 + lr) * EHID + h * 256 + k2 + lg * 8);
        #pragma unroll
        for (int m = 0; m < 4; m++)
          acc2[m][n] = __builtin_amdgcn_mfma_f32_16x16x32_bf16(a2[m], bb, acc2[m][n], 0, 0, 0);
      }
    }
  }
  #pragma unroll
  for (int m = 0; m < 4; m++)
    #pragma unroll
    for (int j = 0; j < 4; j++) {
      int r = m * 16 + lg * 4 + j;
      #pragma unroll
      for (int n = 0; n < 8; n++)
        y[(size_t)(slot0 + r) * D_MODEL + w * 128 + n * 16 + lr] = acc2[m][n][j];
    }
}

// ---------------- combine: out[t] += w0*y[s0] + w1*y[s1] ----------------
__global__ __launch_bounds__(256) void combine_kernel(const float* __restrict__ y, const int* __restrict__ slot_of,
                                                      const float* __restrict__ topw, float* __restrict__ out) {
  int t = blockIdx.x * 4 + (threadIdx.x >> 6);
  int l = threadIdx.x & 63;
  int s0 = slot_of[t * 2], s1 = slot_of[t * 2 + 1];
  float w0 = topw[t * 2], w1 = topw[t * 2 + 1];
  const float* y0 = y + (size_t)s0 * D_MODEL + l * 16;
  const float* y1 = y + (size_t)s1 * D_MODEL + l * 16;
  float* o = out + (size_t)t * D_MODEL + l * 16;
  #pragma unroll
  for (int i = 0; i < 4; i++) {
    fx4 av = *(const fx4*)(y0 + i * 4);
    fx4 bv = *(const fx4*)(y1 + i * 4);
    fx4 d = *(const fx4*)(o + i * 4);
    #pragma unroll
    for (int j = 0; j < 4; j++) d[j] += w0 * av[j] + w1 * bv[j];
    *(fx4*)(o + i * 4) = d;
  }
}

// ---------------- launcher ----------------
#define MB (1u << 20)
extern "C" void kernel_launch(void* const* d_in, const int* in_sizes, int n_in,
                              void* d_out, int out_size, void* d_ws, size_t ws_size,
                              hipStream_t stream) {
  const float* x  = (const float*)d_in[0];
  const float* Wq = (const float*)d_in[1];
  const float* Wk = (const float*)d_in[2];
  const float* Wv = (const float*)d_in[3];
  const float* Wo = (const float*)d_in[4];
  const float* g1 = (const float*)d_in[5];
  const float* b1 = (const float*)d_in[6];
  const float* g2 = (const float*)d_in[7];
  const float* b2 = (const float*)d_in[8];
  const float* Wg = (const float*)d_in[9];
  const float* W1 = (const float*)d_in[10];
  const float* W2 = (const float*)d_in[11];
  float* out = (float*)d_out;

  char* ws = (char*)d_ws;
  _Float16* xn1h = (_Float16*)(ws + 0*MB);     // later aliased as attn hi plane
  _Float16* xn1l = (_Float16*)(ws + 8*MB);     // later aliased as attn lo plane
  _Float16* Wqkh = (_Float16*)(ws + 16*MB);
  _Float16* Wqkl = (_Float16*)(ws + 22*MB);
  _Float16* Woh  = (_Float16*)(ws + 28*MB);
  _Float16* Wol  = (_Float16*)(ws + 30*MB);
  _Float16* qhb  = (_Float16*)(ws + 32*MB);
  _Float16* qlb  = (_Float16*)(ws + 40*MB);
  _Float16* khb  = (_Float16*)(ws + 48*MB);
  _Float16* klb  = (_Float16*)(ws + 56*MB);
  _Float16* vhb  = (_Float16*)(ws + 64*MB);
  _Float16* vlb  = (_Float16*)(ws + 72*MB);
  unsigned short* xn2 = (unsigned short*)(ws + 80*MB);
  unsigned short* W1T = (unsigned short*)(ws + 88*MB);
  unsigned short* W2T = (unsigned short*)(ws + 96*MB);
  char* misc = ws + 104*MB;
  int*   topi    = (int*)(misc);
  float* topw    = (float*)(misc + 32768);
  int*   slot_of = (int*)(misc + 65536);
  int*   cnt     = (int*)(misc + 98304);
  int*   perm    = (int*)(misc + 98368);
  float* ybuf    = (float*)(ws + 32*MB);       // 8704x1024 fp32 (~35.7MB), aliases q/k/v buffers (dead after flash)
  _Float16* attnh = xn1h;
  _Float16* attnl = xn1l;

  // weight prep + routing init (single fused kernel)
  prep_kernel<<<12322, 256, 0, stream>>>(Wq, Wk, Wv, Wo, W1, W2, Wqkh, Wqkl, Woh, Wol, W1T, W2T, cnt, perm);

  // attention path (split fp16, ~fp32 accuracy)
  ln_f16s_kernel<<<TOKENS, 256, 0, stream>>>(x, g1, b1, xn1h, xn1l);
  gemm_qkv_kernel<<<768, 256, 0, stream>>>(xn1h, xn1l, Wqkh, Wqkl, qhb, qlb, khb, klb, vhb, vlb);
  flash_kernel<<<1024, 256, 0, stream>>>(qhb, qlb, khb, klb, vhb, vlb, attnh, attnl);
  gemm_oproj_kernel<<<256, 256, 0, stream>>>(attnh, attnl, Woh, Wol, x, out);

  // MoE path
  gate_kernel<<<1024, 256, 0, stream>>>(out, Wg, g2, b2, xn2, cnt, topi, topw);
  scatter_kernel<<<8, 256, 0, stream>>>(topi, cnt, perm, slot_of);
  moe_ffn_kernel<<<136, 512, 0, stream>>>(xn2, W1T, W2T, cnt, perm, ybuf);
  combine_kernel<<<1024, 256, 0, stream>>>(ybuf, slot_of, topw, out);

  (void)in_sizes; (void)n_in; (void)out_size; (void)ws_size;
}